// Round 17
// baseline (1046.122 us; speedup 1.0000x reference)
//
#include <hip/hip_runtime.h>
#include <hip/hip_bf16.h>
#include <hip/hip_fp8.h>

#define N_USERC 100000
#define N_ITEMC 50000
#define N_TOTALC 150000
#define DC 64
#define NNZ_AC 2000000
#define NNZ_SC 1000000
#define N_TAILC 10000
#define N_HEADC 4000
#define TOPKC 10
#define BATCHC 4096
#define N_NEGC 4
#define CONVF 40.0f

#define RPB 256                                  // rows per bucket (row_local = 8 bits)
#define NB_A ((N_TOTALC + RPB - 1) / RPB)        // 586
#define NB_S ((N_USERC + RPB - 1) / RPB)         // 391
#define IPB 6144                                 // items per partition block
#define PBLK_A ((NNZ_AC + IPB - 1) / IPB)        // 326
#define PBLK_S ((NNZ_SC + IPB - 1) / IPB)        // 163
#define SLAB 4096                                // per-bucket slab capacity
#define FCAP 4096                                // finalize LDS staging capacity (32KB)
#define NCB 32                                   // col blocks in score gemm (4000/128 -> 32)

#define LOSS_BLOCKS (BATCHC / 4)                 // 1024

__device__ __forceinline__ unsigned char F2Q(float f) {
    __hip_fp8_e4m3 q(f);
    return (unsigned char)q.__x;
}
__device__ __forceinline__ float Q2F(unsigned char b) {
    __hip_fp8_e4m3 q;
    q.__x = (__hip_fp8_storage_t)b;
    return (float)q;
}

// ---------------- cursor init: slab bases ----------------
__global__ __launch_bounds__(256) void init_cursors(int* __restrict__ aCur, int* __restrict__ sCur) {
    int i = blockIdx.x * 256 + threadIdx.x;
    if (i < NB_A) aCur[i] = i * SLAB;
    if (i < NB_S) sCur[i] = i * SLAB;
}

// ---------------- partition: block-local counting sort into bucket SLABS (R13 proven form) ----------------
__global__ __launch_bounds__(256) void partition_fused(
    const float* __restrict__ a_vals, const int* __restrict__ a_rows, const int* __restrict__ a_cols,
    const float* __restrict__ s_vals, const int* __restrict__ s_rows, const int* __restrict__ s_cols,
    int* __restrict__ aCur, int* __restrict__ sCur,
    int2* __restrict__ aPack, int2* __restrict__ sPack) {
    __shared__ int h[NB_A];
    __shared__ int cur[NB_A];
    int blk = blockIdx.x;
    const float* vals; const int* rows; const int* cols; int n; int nb; int* gcur; int2* pack; int base;
    if (blk < PBLK_A) { vals = a_vals; rows = a_rows; cols = a_cols; n = NNZ_AC; nb = NB_A; gcur = aCur; pack = aPack; base = blk * IPB; }
    else { vals = s_vals; rows = s_rows; cols = s_cols; n = NNZ_SC; nb = NB_S; gcur = sCur; pack = sPack; base = (blk - PBLK_A) * IPB; }
    int tid = threadIdx.x;
    for (int i = tid; i < nb; i += 256) h[i] = 0;
    __syncthreads();
    for (int k = 0; k < IPB; k += 256) {
        int idx = base + k + tid;
        if (idx < n) atomicAdd(&h[rows[idx] >> 8], 1);
    }
    __syncthreads();
    for (int i = tid; i < nb; i += 256) {
        int c = h[i];
        cur[i] = c ? atomicAdd(&gcur[i], c) : 0;
    }
    __syncthreads();
    for (int k = 0; k < IPB; k += 256) {
        int idx = base + k + tid;
        if (idx < n) {
            int r = rows[idx];
            int b = r >> 8;
            int pos = atomicAdd(&cur[b], 1);
            pack[pos] = make_int2(__float_as_int(vals[idx]), cols[idx] | ((r & 255) << 18));
        }
    }
}

// ---------------- finalize: per-bucket counting sort within slab -> rp_start / rp_end ----------------
__global__ __launch_bounds__(256) void csr_finalize(const int* __restrict__ aEnd, const int* __restrict__ sEnd,
                                                    const int2* __restrict__ aRaw, const int2* __restrict__ sRaw,
                                                    int2* __restrict__ aOut, int2* __restrict__ sOut,
                                                    int* __restrict__ aRs, int* __restrict__ aRe,
                                                    int* __restrict__ sRs, int* __restrict__ sRe) {
    __shared__ int2 ebuf[FCAP];
    __shared__ int cnt_[RPB];
    __shared__ int scn[RPB];
    __shared__ int cursor[RPB];
    int blk = blockIdx.x;
    const int* ends; const int2* raw; int2* outp; int* rs; int* re; int nrows; int b;
    if (blk < NB_A) { ends = aEnd; raw = aRaw; outp = aOut; rs = aRs; re = aRe; nrows = N_TOTALC; b = blk; }
    else { ends = sEnd; raw = sRaw; outp = sOut; rs = sRs; re = sRe; nrows = N_USERC; b = blk - NB_A; }
    int s = b * SLAB;
    int e = ends[b];
    int n = e - s;
    int tid = threadIdx.x;
    bool useLds = (n <= FCAP);
    cnt_[tid] = 0;
    __syncthreads();
    if (useLds) {
        for (int i = tid; i < n; i += 256) {
            int2 en = raw[s + i];
            ebuf[i] = en;
            atomicAdd(&cnt_[(en.y >> 18) & 255], 1);
        }
    } else {
        for (int i = tid; i < n; i += 256)
            atomicAdd(&cnt_[(raw[s + i].y >> 18) & 255], 1);
    }
    __syncthreads();
    scn[tid] = cnt_[tid];
    __syncthreads();
    for (int off = 1; off < RPB; off <<= 1) {
        int t = (tid >= off) ? scn[tid - off] : 0;
        __syncthreads();
        scn[tid] += t;
        __syncthreads();
    }
    {
        int inc = scn[tid];
        int ex = inc - cnt_[tid];
        cursor[tid] = ex;
        int row = (b << 8) + tid;
        if (row < nrows) { rs[row] = s + ex; re[row] = s + inc; }
    }
    __syncthreads();
    if (useLds) {
        for (int i = tid; i < n; i += 256) {
            int2 en = ebuf[i];
            int r = (en.y >> 18) & 255;
            int pos = atomicAdd(&cursor[r], 1);
            outp[s + pos] = make_int2(en.x, en.y & 0x3FFFF);
        }
    } else {
        for (int i = tid; i < n; i += 256) {
            int2 en = raw[s + i];
            int r = (en.y >> 18) & 255;
            int pos = atomicAdd(&cursor[r], 1);
            outp[s + pos] = make_int2(en.x, en.y & 0x3FFFF);
        }
    }
}

// ---------------- concat + fp32->fp8 convert ----------------
__global__ __launch_bounds__(256) void to_f8_concat(const float* __restrict__ xu, const float* __restrict__ xi,
                                                    unsigned char* __restrict__ out) {
    size_t i4 = (size_t)blockIdx.x * 256 + threadIdx.x;
    const size_t NU4 = (size_t)N_USERC * 16;
    const size_t NT4 = (size_t)N_TOTALC * 16;
    if (i4 >= NT4) return;
    float4 v = (i4 < NU4) ? ((const float4*)xu)[i4] : ((const float4*)xi)[i4 - NU4];
    uchar4 q;
    q.x = F2Q(v.x); q.y = F2Q(v.y); q.z = F2Q(v.z); q.w = F2Q(v.w);
    ((uchar4*)out)[i4] = q;
}

// ---------------- CSR SpMM, fp8 pair-gather, clamp-predicated 16-wide body ----------------
__global__ __launch_bounds__(256) void spmm_f8(const int* __restrict__ rps, const int* __restrict__ rpe,
                                               const int2* __restrict__ pack,
                                               const unsigned char* __restrict__ xq,
                                               float* __restrict__ y,
                                               unsigned char* __restrict__ yq, int nrows) {
    int w = (blockIdx.x * blockDim.x + threadIdx.x) >> 6;
    int lane = threadIdx.x & 63;
    if (w >= nrows) return;
    int half = lane >> 5;
    int sl = lane & 31;
    int s = rps[w], e = rpe[w];
    float a0 = 0.f, a1 = 0.f, b0 = 0.f, b1 = 0.f;
    float c0 = 0.f, c1 = 0.f, d0 = 0.f, d1 = 0.f;
    if (e > s) {
        int last = e - 1;
        for (int j = s; j < e; j += 16) {
            int k0 = j + half, k1 = k0 + 2, k2 = k0 + 4, k3 = k0 + 6;
            int k4 = k0 + 8, k5 = k0 + 10, k6 = k0 + 12, k7 = k0 + 14;
            int2 e0 = pack[min(k0, last)], e1 = pack[min(k1, last)];
            int2 e2 = pack[min(k2, last)], e3 = pack[min(k3, last)];
            int2 e4 = pack[min(k4, last)], e5 = pack[min(k5, last)];
            int2 e6 = pack[min(k6, last)], e7 = pack[min(k7, last)];
            unsigned short g0 = *(const unsigned short*)&xq[(size_t)e0.y * 64 + sl * 2];
            unsigned short g1 = *(const unsigned short*)&xq[(size_t)e1.y * 64 + sl * 2];
            unsigned short g2 = *(const unsigned short*)&xq[(size_t)e2.y * 64 + sl * 2];
            unsigned short g3 = *(const unsigned short*)&xq[(size_t)e3.y * 64 + sl * 2];
            unsigned short g4 = *(const unsigned short*)&xq[(size_t)e4.y * 64 + sl * 2];
            unsigned short g5 = *(const unsigned short*)&xq[(size_t)e5.y * 64 + sl * 2];
            unsigned short g6 = *(const unsigned short*)&xq[(size_t)e6.y * 64 + sl * 2];
            unsigned short g7 = *(const unsigned short*)&xq[(size_t)e7.y * 64 + sl * 2];
            float v0 = (k0 <= last) ? __int_as_float(e0.x) : 0.f;
            float v1 = (k1 <= last) ? __int_as_float(e1.x) : 0.f;
            float v2 = (k2 <= last) ? __int_as_float(e2.x) : 0.f;
            float v3 = (k3 <= last) ? __int_as_float(e3.x) : 0.f;
            float v4 = (k4 <= last) ? __int_as_float(e4.x) : 0.f;
            float v5 = (k5 <= last) ? __int_as_float(e5.x) : 0.f;
            float v6 = (k6 <= last) ? __int_as_float(e6.x) : 0.f;
            float v7 = (k7 <= last) ? __int_as_float(e7.x) : 0.f;
            a0 += v0 * Q2F((unsigned char)(g0 & 255)); a1 += v0 * Q2F((unsigned char)(g0 >> 8));
            b0 += v1 * Q2F((unsigned char)(g1 & 255)); b1 += v1 * Q2F((unsigned char)(g1 >> 8));
            c0 += v2 * Q2F((unsigned char)(g2 & 255)); c1 += v2 * Q2F((unsigned char)(g2 >> 8));
            d0 += v3 * Q2F((unsigned char)(g3 & 255)); d1 += v3 * Q2F((unsigned char)(g3 >> 8));
            a0 += v4 * Q2F((unsigned char)(g4 & 255)); a1 += v4 * Q2F((unsigned char)(g4 >> 8));
            b0 += v5 * Q2F((unsigned char)(g5 & 255)); b1 += v5 * Q2F((unsigned char)(g5 >> 8));
            c0 += v6 * Q2F((unsigned char)(g6 & 255)); c1 += v6 * Q2F((unsigned char)(g6 >> 8));
            d0 += v7 * Q2F((unsigned char)(g7 & 255)); d1 += v7 * Q2F((unsigned char)(g7 >> 8));
        }
    }
    float r0 = (a0 + b0) + (c0 + d0);
    float r1 = (a1 + b1) + (c1 + d1);
    r0 += __shfl_xor(r0, 32, 64);
    r1 += __shfl_xor(r1, 32, 64);
    if (lane < 32) {
        if (y) ((float2*)y)[(size_t)w * 32 + sl] = make_float2(r0, r1);
        if (yq) { uchar2 q; q.x = F2Q(r0); q.y = F2Q(r1); ((uchar2*)yq)[(size_t)w * 32 + sl] = q; }
    }
}

// ---------------- collapsed encoder ----------------
__global__ __launch_bounds__(256) void mc_kernel(const float* __restrict__ w0, const float* __restrict__ b0,
                                                 const float* __restrict__ w2, const float* __restrict__ b2,
                                                 float* __restrict__ Mrm, float* __restrict__ cvec) {
    int idx = blockIdx.x * 256 + threadIdx.x;
    if (idx < 4096) {
        int j = idx >> 6, d = idx & 63;
        float acc = 0.f;
        for (int k = 0; k < 256; ++k) acc += w2[j * 256 + k] * w0[k * 64 + d];
        Mrm[idx] = acc;
    } else if (idx < 4160) {
        int i = idx - 4096;
        float acc = b2[i];
        for (int k = 0; k < 256; ++k) acc += w2[i * 256 + k] * b0[k];
        cvec[i] = acc;
    }
}

// enc(f) = f @ Mrm^T + cvec ; one wave per row; fused tail+head
__global__ __launch_bounds__(256) void enc2_fused(const float* __restrict__ emb,
                                                  const int* __restrict__ tail_idx, const int* __restrict__ head_idx,
                                                  const float* __restrict__ Mrm, const float* __restrict__ cvec,
                                                  float* __restrict__ tail_e, float* __restrict__ top_e) {
    __shared__ float fsh[4][64];
    int wv = threadIdx.x >> 6, lane = threadIdx.x & 63;
    int r = blockIdx.x * 4 + wv;
    int item;
    float* outp;
    if (r < N_TAILC) { item = tail_idx[r]; outp = tail_e + (size_t)r * 64; }
    else if (r < N_TAILC + N_HEADC) { item = head_idx[r - N_TAILC]; outp = top_e + (size_t)(r - N_TAILC) * 64; }
    else { item = -1; outp = nullptr; }
    if (item >= 0) fsh[wv][lane] = emb[(size_t)item * 64 + lane];
    __syncthreads();
    if (item < 0) return;
    float acc = cvec[lane];
#pragma unroll
    for (int d4 = 0; d4 < 64; d4 += 4) {
        float4 m4 = *(const float4*)&Mrm[lane * 64 + d4];
        float4 f4 = *(const float4*)&fsh[wv][d4];
        acc += m4.x * f4.x + m4.y * f4.y + m4.z * f4.z + m4.w * f4.w;
    }
    outp[lane] = acc;
}

// ---------------- fused score GEMM + per-block top-10 candidates ----------------
// block tile 128x128; thread tile 8x8; epilogue: per-row top-10 over the block's 128 cols
// cand[(row*NCB + bx)*10 + k] = (val_bits, global_col)
#define ESEL(ek, kk) { if (ek > lv) { lv = ek; lk = kk; } }
__global__ __launch_bounds__(256) void score_gemm_topk(const float* __restrict__ A,
                                                       const float* __restrict__ B,
                                                       int2* __restrict__ cand, int M) {
    __shared__ float As[32][132];
    __shared__ float Bs[32][132];
    int tid = threadIdx.x;
    int tx = tid & 15, ty = tid >> 4;
    int rowbase = blockIdx.y * 128;
    int colbase = blockIdx.x * 128;
    float acc[8][8];
#pragma unroll
    for (int i = 0; i < 8; ++i)
#pragma unroll
        for (int j = 0; j < 8; ++j) acc[i][j] = 0.f;

    for (int k0 = 0; k0 < 64; k0 += 32) {
        __syncthreads();
#pragma unroll
        for (int i = 0; i < 4; ++i) {
            int f = tid + i * 256;
            int r = f >> 3;
            int kq = (f & 7) << 2;
            int grow = rowbase + r;
            float4 av = (grow < M) ? *(const float4*)&A[(size_t)grow * 64 + k0 + kq]
                                   : make_float4(0.f, 0.f, 0.f, 0.f);
            As[kq + 0][r] = av.x; As[kq + 1][r] = av.y; As[kq + 2][r] = av.z; As[kq + 3][r] = av.w;
            int gcol = colbase + r;
            float4 bv = (gcol < N_HEADC) ? *(const float4*)&B[(size_t)gcol * 64 + k0 + kq]
                                         : make_float4(0.f, 0.f, 0.f, 0.f);
            Bs[kq + 0][r] = bv.x; Bs[kq + 1][r] = bv.y; Bs[kq + 2][r] = bv.z; Bs[kq + 3][r] = bv.w;
        }
        __syncthreads();
#pragma unroll
        for (int k = 0; k < 32; ++k) {
            float a[8], b[8];
#pragma unroll
            for (int i = 0; i < 8; ++i) a[i] = As[k][ty + 16 * i];
#pragma unroll
            for (int j = 0; j < 8; ++j) b[j] = Bs[k][tx + 16 * j];
#pragma unroll
            for (int i = 0; i < 8; ++i)
#pragma unroll
                for (int j = 0; j < 8; ++j) acc[i][j] += a[i] * b[j];
        }
    }
    // epilogue: per-row top-10 across the 16 tx-threads (128 cols), named scalars only
#pragma unroll
    for (int i = 0; i < 8; ++i) {
        int grow = rowbase + ty + 16 * i;
        float e0 = (colbase + tx +   0 < N_HEADC) ? acc[i][0] : -1e30f;
        float e1 = (colbase + tx +  16 < N_HEADC) ? acc[i][1] : -1e30f;
        float e2 = (colbase + tx +  32 < N_HEADC) ? acc[i][2] : -1e30f;
        float e3 = (colbase + tx +  48 < N_HEADC) ? acc[i][3] : -1e30f;
        float e4 = (colbase + tx +  64 < N_HEADC) ? acc[i][4] : -1e30f;
        float e5 = (colbase + tx +  80 < N_HEADC) ? acc[i][5] : -1e30f;
        float e6 = (colbase + tx +  96 < N_HEADC) ? acc[i][6] : -1e30f;
        float e7 = (colbase + tx + 112 < N_HEADC) ? acc[i][7] : -1e30f;
        float outv = -1e30f;
        int outid = colbase;
#pragma unroll
        for (int r = 0; r < TOPKC; ++r) {
            float lv = e0; int lk = 0;
            ESEL(e1, 1) ESEL(e2, 2) ESEL(e3, 3) ESEL(e4, 4) ESEL(e5, 5) ESEL(e6, 6) ESEL(e7, 7)
            float cv = lv;
            int ci = colbase + tx + (lk << 4);
#pragma unroll
            for (int m = 1; m < 16; m <<= 1) {
                float ov = __shfl_xor(cv, m, 64);
                int oi = __shfl_xor(ci, m, 64);
                if (ov > cv || (ov == cv && oi < ci)) { cv = ov; ci = oi; }
            }
            int lcol = ci - colbase;
            if ((lcol & 15) == tx) {
                int kk = lcol >> 4;
                if (kk == 0) e0 = -3e30f;
                else if (kk == 1) e1 = -3e30f;
                else if (kk == 2) e2 = -3e30f;
                else if (kk == 3) e3 = -3e30f;
                else if (kk == 4) e4 = -3e30f;
                else if (kk == 5) e5 = -3e30f;
                else if (kk == 6) e6 = -3e30f;
                else e7 = -3e30f;
            }
            if (tx == r) { outv = cv; outid = ci; }
        }
        if (grow < M && tx < TOPKC)
            cand[((size_t)grow * NCB + blockIdx.x) * TOPKC + tx] = make_int2(__float_as_int(outv), outid);
    }
}

// ---------------- merge: per row, top-10 of NCB*10=320 candidates -> ig weights ----------------
#define BUB(vk, ik) { if (cv > vk) { float tf = vk; vk = cv; cv = tf; int ti = ik; ik = ci; ci = ti; } }
#define TINS(sc, idx) { float sc_ = (sc); if (sc_ > v9) { float cv = sc_; int ci = (idx); \
    BUB(v0, i0) BUB(v1, i1) BUB(v2, i2) BUB(v3, i3) BUB(v4, i4) \
    BUB(v5, i5) BUB(v6, i6) BUB(v7, i7) BUB(v8, i8) BUB(v9, i9) } }

__global__ __launch_bounds__(256) void topk_merge(const int2* __restrict__ cand,
                                                  const int* __restrict__ head_idx,
                                                  int* __restrict__ ig_cols, float* __restrict__ ig_vals) {
    int w = (blockIdx.x * blockDim.x + threadIdx.x) >> 6;
    int lane = threadIdx.x & 63;
    if (w >= N_TAILC) return;
    const int2* crow = cand + (size_t)w * (NCB * TOPKC);
    float v0 = -1e30f, v1 = -1e30f, v2 = -1e30f, v3 = -1e30f, v4 = -1e30f;
    float v5 = -1e30f, v6 = -1e30f, v7 = -1e30f, v8 = -1e30f, v9 = -1e30f;
    int i0 = -1, i1 = -1, i2 = -1, i3 = -1, i4 = -1;
    int i5 = -1, i6 = -1, i7 = -1, i8 = -1, i9 = -1;
#pragma unroll
    for (int t = 0; t < 5; ++t) {               // 320 = 5 * 64
        int2 c = crow[lane + (t << 6)];
        TINS(__int_as_float(c.x), c.y)
    }
    float ssum = 0.f;
    float outv = 0.f;
    int outid = -1;
#pragma unroll
    for (int r = 0; r < TOPKC; ++r) {
        float cv = v0;
        int ci = i0;
        int wl = lane;
#pragma unroll
        for (int m = 1; m < 64; m <<= 1) {
            float ov = __shfl_xor(cv, m, 64);
            int oi = __shfl_xor(ci, m, 64);
            int ol = __shfl_xor(wl, m, 64);
            if (ov > cv || (ov == cv && ol < wl)) { cv = ov; ci = oi; wl = ol; }
        }
        if (wl == lane) {
            v0 = v1; i0 = i1; v1 = v2; i1 = i2; v2 = v3; i2 = i3;
            v3 = v4; i3 = i4; v4 = v5; i4 = i5; v5 = v6; i5 = i6;
            v6 = v7; i6 = i7; v7 = v8; i7 = i8; v8 = v9; i8 = i9;
            v9 = -1e30f; i9 = -1;
        }
        ssum += 1.f / (1.f + expf(-cv));
        if (lane == r) { outv = cv; outid = ci; }
    }
    if (lane < TOPKC) {
        float s = 1.f / (1.f + expf(-outv));
        float wgt = s / (ssum + 1.f);
        ig_vals[w * TOPKC + lane] = wgt;
        ig_cols[w * TOPKC + lane] = head_idx[outid];
    }
}

// ---------------- item_enh: one wave per tail row, register accumulate, 1 atomic per lane ----------------
__global__ __launch_bounds__(256) void ig_spmm_kernel(const int* __restrict__ tail_idx,
                                                      const int* __restrict__ ig_cols,
                                                      const float* __restrict__ ig_vals,
                                                      const float* __restrict__ items,
                                                      float* __restrict__ enh) {
    int r = (blockIdx.x * blockDim.x + threadIdx.x) >> 6;
    int lane = threadIdx.x & 63;
    if (r >= N_TAILC) return;
    int row = tail_idx[r];
    float acc = 0.f;
#pragma unroll
    for (int k = 0; k < TOPKC; ++k) {
        int col = ig_cols[r * TOPKC + k];
        float wgt = ig_vals[r * TOPKC + k];
        acc += wgt * items[(size_t)col * 64 + lane];
    }
    atomicAdd(&enh[(size_t)row * 64 + lane], acc);
}

// ---------------- loss: one wave per sample, per-block partial outputs ----------------
__global__ __launch_bounds__(256) void loss_kernel(const float* __restrict__ u0, const float* __restrict__ u1,
                                                   const float* __restrict__ u2, const float* __restrict__ items,
                                                   const float* __restrict__ enh, const float* __restrict__ deg,
                                                   const float* __restrict__ user_emb, const float* __restrict__ item_emb,
                                                   const int* __restrict__ bu, const int* __restrict__ bp,
                                                   const int* __restrict__ bn, float* __restrict__ part) {
    __shared__ float lsum[4], rsum[4];
    int w = (blockIdx.x * blockDim.x + threadIdx.x) >> 6;
    int wv = threadIdx.x >> 6;
    int lane = threadIdx.x & 63;
    int uu = bu[w], pp = bp[w];
    float ue = (u0[uu * 64 + lane] + u1[uu * 64 + lane] + u2[uu * 64 + lane]) * (1.f / 3.f);
    float swp = CONVF / (CONVF + expf(deg[pp] * (1.f / CONVF)));
    float pe = items[pp * 64 + lane] + swp * enh[pp * 64 + lane];
    float ps = ue * pe;
    float ns = 0.f;
    float u0e = user_emb[uu * 64 + lane];
    float p0e = item_emb[pp * 64 + lane];
    float reg = u0e * u0e + p0e * p0e;
#pragma unroll
    for (int k = 0; k < N_NEGC; ++k) {
        int nn = bn[w * N_NEGC + k];
        float swn = CONVF / (CONVF + expf(deg[nn] * (1.f / CONVF)));
        float nv = items[nn * 64 + lane] + swn * enh[nn * 64 + lane];
        ns += ue * nv;
        float n0 = item_emb[nn * 64 + lane];
        reg += n0 * n0;
    }
#pragma unroll
    for (int m = 32; m >= 1; m >>= 1) {
        ps += __shfl_xor(ps, m, 64);
        ns += __shfl_xor(ns, m, 64);
        reg += __shfl_xor(reg, m, 64);
    }
    if (lane == 0) {
        float x = ns * (1.f / N_NEGC) - ps;
        float sp = (x > 0.f) ? (x + log1pf(expf(-x))) : log1pf(expf(x));
        lsum[wv] = sp;
        rsum[wv] = reg;
    }
    __syncthreads();
    if (threadIdx.x == 0) {
        part[blockIdx.x] = lsum[0] + lsum[1] + lsum[2] + lsum[3];
        part[LOSS_BLOCKS + blockIdx.x] = rsum[0] + rsum[1] + rsum[2] + rsum[3];
    }
}

// single-block final reduce: out[0]=loss, out[1]=reg
__global__ __launch_bounds__(256) void loss_reduce(const float* __restrict__ part, float* __restrict__ out) {
    __shared__ float l[256], r[256];
    int tid = threadIdx.x;
    float a = 0.f, b = 0.f;
    for (int i = tid; i < LOSS_BLOCKS; i += 256) {
        a += part[i];
        b += part[LOSS_BLOCKS + i];
    }
    l[tid] = a; r[tid] = b;
    __syncthreads();
    for (int off = 128; off >= 1; off >>= 1) {
        if (tid < off) { l[tid] += l[tid + off]; r[tid] += r[tid + off]; }
        __syncthreads();
    }
    if (tid == 0) {
        out[0] = l[0] * (1.f / BATCHC);
        out[1] = 0.5f * r[0] * (1.f / BATCHC);
    }
}

extern "C" void kernel_launch(void* const* d_in, const int* in_sizes, int n_in,
                              void* d_out, int out_size, void* d_ws, size_t ws_size,
                              hipStream_t stream) {
    const float* user_emb = (const float*)d_in[0];
    const float* item_emb = (const float*)d_in[1];
    const float* w0 = (const float*)d_in[2];
    const float* b0 = (const float*)d_in[3];
    const float* w2 = (const float*)d_in[4];
    const float* b2 = (const float*)d_in[5];
    const float* a_vals = (const float*)d_in[6];
    const float* s_vals = (const float*)d_in[7];
    const float* item_degree = (const float*)d_in[8];
    const int* a_rows = (const int*)d_in[9];
    const int* a_cols = (const int*)d_in[10];
    const int* s_rows = (const int*)d_in[11];
    const int* s_cols = (const int*)d_in[12];
    const int* tail_idx = (const int*)d_in[13];
    const int* head_idx = (const int*)d_in[14];
    const int* batch_user = (const int*)d_in[15];
    const int* batch_pos = (const int*)d_in[16];
    const int* batch_neg = (const int*)d_in[17];
    float* out = (float*)d_out;

    // ---- workspace carve ----
    char* p = (char*)d_ws;
    auto carve = [&](size_t bytes) -> void* {
        void* r = (void*)p;
        p += (bytes + 255) & ~size_t(255);
        return r;
    };
    float* embB = (float*)carve((size_t)N_TOTALC * 64 * 4);   // final all_emb (fp32)
    float* u1 = (float*)carve((size_t)N_USERC * 64 * 4);
    float* u2 = (float*)carve((size_t)N_USERC * 64 * 4);
    float* enh = (float*)carve((size_t)N_ITEMC * 64 * 4);
    float* tail_e = (float*)carve((size_t)N_TAILC * 64 * 4);
    float* top_e = (float*)carve((size_t)N_HEADC * 64 * 4);
    int2* aSort = (int2*)carve((size_t)NB_A * SLAB * 8);      // slab layout, row-grouped
    int2* sSort = (int2*)carve((size_t)NB_S * SLAB * 8);
    int* aRs = (int*)carve((size_t)N_TOTALC * 4);
    int* aRe = (int*)carve((size_t)N_TOTALC * 4);
    int* sRs = (int*)carve((size_t)N_USERC * 4);
    int* sRe = (int*)carve((size_t)N_USERC * 4);
    int* aCur = (int*)carve((size_t)NB_A * 4);
    int* sCur = (int*)carve((size_t)NB_S * 4);
    int* ig_cols_buf = (int*)carve((size_t)N_TAILC * TOPKC * 4);
    float* ig_vals_buf = (float*)carve((size_t)N_TAILC * TOPKC * 4);
    float* Mrm = (float*)carve(64 * 64 * 4);
    float* cvec = (float*)carve(64 * 4);
    float* loss_part = (float*)carve((size_t)LOSS_BLOCKS * 2 * 4);
    char* scratch = (char*)carve((size_t)40 * 1024 * 1024);   // 40MB multi-phase region
    // aliases within the scratch region (dead across phases):
    int2* aPackRaw = (int2*)scratch;                          // build phase: slab raw (19.2MB)
    int2* sPackRaw = aPackRaw + (size_t)NB_A * SLAB;          // +12.8MB = 32MB < 40MB
    int2* cand = (int2*)scratch;                              // score phase: candidates (25.6MB)
    // after merge: fp8 tables (4 x 9.6MB = 38.4MB < 40MB)
    unsigned char* f0 = (unsigned char*)scratch;              // concat input, e4m3
    unsigned char* f1 = f0 + (size_t)N_TOTALC * 64;           // L1 out
    unsigned char* f2 = f1 + (size_t)N_TOTALC * 64;           // L2 out
    unsigned char* f3 = f2 + (size_t)N_TOTALC * 64;           // L3 out
    unsigned char* uF1 = f0;                                  // S1 out (f0 dead after L1)

    // ---- slab CSR build (A + S): no histogram pass ----
    init_cursors<<<(NB_A + 255) / 256, 256, 0, stream>>>(aCur, sCur);
    partition_fused<<<PBLK_A + PBLK_S, 256, 0, stream>>>(a_vals, a_rows, a_cols,
                                                         s_vals, s_rows, s_cols,
                                                         aCur, sCur, aPackRaw, sPackRaw);
    // aCur/sCur now hold bucket END offsets within slabs
    csr_finalize<<<NB_A + NB_S, 256, 0, stream>>>(aCur, sCur, aPackRaw, sPackRaw,
                                                  aSort, sSort, aRs, aRe, sRs, sRe);

    // ---- collapsed encoder (tail + head fused) ----
    mc_kernel<<<17, 256, 0, stream>>>(w0, b0, w2, b2, Mrm, cvec);
    enc2_fused<<<(N_TAILC + N_HEADC + 3) / 4, 256, 0, stream>>>(item_emb, tail_idx, head_idx, Mrm, cvec, tail_e, top_e);

    // ---- fused score GEMM + per-block top-10, then merge (no scores materialization) ----
    score_gemm_topk<<<dim3(NCB, (N_TAILC + 127) / 128), 256, 0, stream>>>(tail_e, top_e, cand, N_TAILC);
    topk_merge<<<(N_TAILC + 3) / 4, 256, 0, stream>>>(cand, head_idx, ig_cols_buf, ig_vals_buf);

    // ---- fp8 concat input table (cand dead from here) ----
    to_f8_concat<<<((N_TOTALC * 16) + 255) / 256, 256, 0, stream>>>(user_emb, item_emb, f0);

    // ---- 3 A-layers, fp8 clamp-predicated gathers; only L3 materializes fp32 ----
    {
        int blocks = (N_TOTALC + 3) / 4;
        spmm_f8<<<blocks, 256, 0, stream>>>(aRs, aRe, aSort, f0, nullptr, f1, N_TOTALC);  // L1
        spmm_f8<<<blocks, 256, 0, stream>>>(aRs, aRe, aSort, f1, nullptr, f2, N_TOTALC);  // L2
        spmm_f8<<<blocks, 256, 0, stream>>>(aRs, aRe, aSort, f2, embB, f3, N_TOTALC);     // L3
    }
    const float* u0 = embB;
    const float* items = embB + (size_t)N_USERC * 64;

    // ---- 2 S-layers on users ----
    {
        int blocks = (N_USERC + 3) / 4;
        spmm_f8<<<blocks, 256, 0, stream>>>(sRs, sRe, sSort, f3, u1, uF1, N_USERC);       // S1
        spmm_f8<<<blocks, 256, 0, stream>>>(sRs, sRe, sSort, uF1, u2, nullptr, N_USERC);  // S2
    }

    // ---- item enhancement ----
    hipMemsetAsync(enh, 0, (size_t)N_ITEMC * 64 * 4, stream);
    ig_spmm_kernel<<<(N_TAILC + 3) / 4, 256, 0, stream>>>(tail_idx, ig_cols_buf, ig_vals_buf, items, enh);

    // ---- loss + reg: per-block partials then single-block reduce ----
    loss_kernel<<<LOSS_BLOCKS, 256, 0, stream>>>(u0, u1, u2, items, enh, item_degree,
                                                 user_emb, item_emb, batch_user, batch_pos, batch_neg, loss_part);
    loss_reduce<<<1, 256, 0, stream>>>(loss_part, out);
}

// Round 18
// 736.495 us; speedup vs baseline: 1.4204x; 1.4204x over previous
//
#include <hip/hip_runtime.h>
#include <hip/hip_bf16.h>
#include <hip/hip_fp8.h>

#define N_USERC 100000
#define N_ITEMC 50000
#define N_TOTALC 150000
#define DC 64
#define NNZ_AC 2000000
#define NNZ_SC 1000000
#define N_TAILC 10000
#define N_HEADC 4000
#define TOPKC 10
#define BATCHC 4096
#define N_NEGC 4
#define CONVF 40.0f
#define CHUNK_ROWS 2500

#define RPB 256                                  // rows per bucket (row_local = 8 bits)
#define NB_A ((N_TOTALC + RPB - 1) / RPB)        // 586
#define NB_S ((N_USERC + RPB - 1) / RPB)         // 391
#define IPB 6144                                 // items per partition block
#define PBLK_A ((NNZ_AC + IPB - 1) / IPB)        // 326
#define PBLK_S ((NNZ_SC + IPB - 1) / IPB)        // 163
#define SLAB 4096                                // per-bucket slab capacity
#define FCAP 4096                                // finalize LDS staging capacity (32KB)

#define LOSS_BLOCKS (BATCHC / 4)                 // 1024

__device__ __forceinline__ unsigned char F2Q(float f) {
    __hip_fp8_e4m3 q(f);
    return (unsigned char)q.__x;
}
__device__ __forceinline__ float Q2F(unsigned char b) {
    __hip_fp8_e4m3 q;
    q.__x = (__hip_fp8_storage_t)b;
    return (float)q;
}

// ---------------- cursor init: slab bases ----------------
__global__ __launch_bounds__(256) void init_cursors(int* __restrict__ aCur, int* __restrict__ sCur) {
    int i = blockIdx.x * 256 + threadIdx.x;
    if (i < NB_A) aCur[i] = i * SLAB;
    if (i < NB_S) sCur[i] = i * SLAB;
}

// ---------------- partition: block-local counting sort into bucket SLABS (R13 proven form) ----------------
__global__ __launch_bounds__(256) void partition_fused(
    const float* __restrict__ a_vals, const int* __restrict__ a_rows, const int* __restrict__ a_cols,
    const float* __restrict__ s_vals, const int* __restrict__ s_rows, const int* __restrict__ s_cols,
    int* __restrict__ aCur, int* __restrict__ sCur,
    int2* __restrict__ aPack, int2* __restrict__ sPack) {
    __shared__ int h[NB_A];
    __shared__ int cur[NB_A];
    int blk = blockIdx.x;
    const float* vals; const int* rows; const int* cols; int n; int nb; int* gcur; int2* pack; int base;
    if (blk < PBLK_A) { vals = a_vals; rows = a_rows; cols = a_cols; n = NNZ_AC; nb = NB_A; gcur = aCur; pack = aPack; base = blk * IPB; }
    else { vals = s_vals; rows = s_rows; cols = s_cols; n = NNZ_SC; nb = NB_S; gcur = sCur; pack = sPack; base = (blk - PBLK_A) * IPB; }
    int tid = threadIdx.x;
    for (int i = tid; i < nb; i += 256) h[i] = 0;
    __syncthreads();
    for (int k = 0; k < IPB; k += 256) {
        int idx = base + k + tid;
        if (idx < n) atomicAdd(&h[rows[idx] >> 8], 1);
    }
    __syncthreads();
    for (int i = tid; i < nb; i += 256) {
        int c = h[i];
        cur[i] = c ? atomicAdd(&gcur[i], c) : 0;
    }
    __syncthreads();
    for (int k = 0; k < IPB; k += 256) {
        int idx = base + k + tid;
        if (idx < n) {
            int r = rows[idx];
            int b = r >> 8;
            int pos = atomicAdd(&cur[b], 1);
            pack[pos] = make_int2(__float_as_int(vals[idx]), cols[idx] | ((r & 255) << 18));
        }
    }
}

// ---------------- finalize: per-bucket counting sort within slab -> rp_start / rp_end ----------------
__global__ __launch_bounds__(256) void csr_finalize(const int* __restrict__ aEnd, const int* __restrict__ sEnd,
                                                    const int2* __restrict__ aRaw, const int2* __restrict__ sRaw,
                                                    int2* __restrict__ aOut, int2* __restrict__ sOut,
                                                    int* __restrict__ aRs, int* __restrict__ aRe,
                                                    int* __restrict__ sRs, int* __restrict__ sRe) {
    __shared__ int2 ebuf[FCAP];
    __shared__ int cnt_[RPB];
    __shared__ int scn[RPB];
    __shared__ int cursor[RPB];
    int blk = blockIdx.x;
    const int* ends; const int2* raw; int2* outp; int* rs; int* re; int nrows; int b;
    if (blk < NB_A) { ends = aEnd; raw = aRaw; outp = aOut; rs = aRs; re = aRe; nrows = N_TOTALC; b = blk; }
    else { ends = sEnd; raw = sRaw; outp = sOut; rs = sRs; re = sRe; nrows = N_USERC; b = blk - NB_A; }
    int s = b * SLAB;
    int e = ends[b];
    int n = e - s;
    int tid = threadIdx.x;
    bool useLds = (n <= FCAP);
    cnt_[tid] = 0;
    __syncthreads();
    if (useLds) {
        for (int i = tid; i < n; i += 256) {
            int2 en = raw[s + i];
            ebuf[i] = en;
            atomicAdd(&cnt_[(en.y >> 18) & 255], 1);
        }
    } else {
        for (int i = tid; i < n; i += 256)
            atomicAdd(&cnt_[(raw[s + i].y >> 18) & 255], 1);
    }
    __syncthreads();
    scn[tid] = cnt_[tid];
    __syncthreads();
    for (int off = 1; off < RPB; off <<= 1) {
        int t = (tid >= off) ? scn[tid - off] : 0;
        __syncthreads();
        scn[tid] += t;
        __syncthreads();
    }
    {
        int inc = scn[tid];
        int ex = inc - cnt_[tid];
        cursor[tid] = ex;
        int row = (b << 8) + tid;
        if (row < nrows) { rs[row] = s + ex; re[row] = s + inc; }
    }
    __syncthreads();
    if (useLds) {
        for (int i = tid; i < n; i += 256) {
            int2 en = ebuf[i];
            int r = (en.y >> 18) & 255;
            int pos = atomicAdd(&cursor[r], 1);
            outp[s + pos] = make_int2(en.x, en.y & 0x3FFFF);
        }
    } else {
        for (int i = tid; i < n; i += 256) {
            int2 en = raw[s + i];
            int r = (en.y >> 18) & 255;
            int pos = atomicAdd(&cursor[r], 1);
            outp[s + pos] = make_int2(en.x, en.y & 0x3FFFF);
        }
    }
}

// ---------------- concat + fp32->fp8 convert ----------------
__global__ __launch_bounds__(256) void to_f8_concat(const float* __restrict__ xu, const float* __restrict__ xi,
                                                    unsigned char* __restrict__ out) {
    size_t i4 = (size_t)blockIdx.x * 256 + threadIdx.x;
    const size_t NU4 = (size_t)N_USERC * 16;
    const size_t NT4 = (size_t)N_TOTALC * 16;
    if (i4 >= NT4) return;
    float4 v = (i4 < NU4) ? ((const float4*)xu)[i4] : ((const float4*)xi)[i4 - NU4];
    uchar4 q;
    q.x = F2Q(v.x); q.y = F2Q(v.y); q.z = F2Q(v.z); q.w = F2Q(v.w);
    ((uchar4*)out)[i4] = q;
}

// ---------------- CSR SpMM, fp8 pair-gather, clamp-predicated 16-wide body ----------------
__global__ __launch_bounds__(256) void spmm_f8(const int* __restrict__ rps, const int* __restrict__ rpe,
                                               const int2* __restrict__ pack,
                                               const unsigned char* __restrict__ xq,
                                               float* __restrict__ y,
                                               unsigned char* __restrict__ yq, int nrows) {
    int w = (blockIdx.x * blockDim.x + threadIdx.x) >> 6;
    int lane = threadIdx.x & 63;
    if (w >= nrows) return;
    int half = lane >> 5;
    int sl = lane & 31;
    int s = rps[w], e = rpe[w];
    float a0 = 0.f, a1 = 0.f, b0 = 0.f, b1 = 0.f;
    float c0 = 0.f, c1 = 0.f, d0 = 0.f, d1 = 0.f;
    if (e > s) {
        int last = e - 1;
        for (int j = s; j < e; j += 16) {
            int k0 = j + half, k1 = k0 + 2, k2 = k0 + 4, k3 = k0 + 6;
            int k4 = k0 + 8, k5 = k0 + 10, k6 = k0 + 12, k7 = k0 + 14;
            int2 e0 = pack[min(k0, last)], e1 = pack[min(k1, last)];
            int2 e2 = pack[min(k2, last)], e3 = pack[min(k3, last)];
            int2 e4 = pack[min(k4, last)], e5 = pack[min(k5, last)];
            int2 e6 = pack[min(k6, last)], e7 = pack[min(k7, last)];
            unsigned short g0 = *(const unsigned short*)&xq[(size_t)e0.y * 64 + sl * 2];
            unsigned short g1 = *(const unsigned short*)&xq[(size_t)e1.y * 64 + sl * 2];
            unsigned short g2 = *(const unsigned short*)&xq[(size_t)e2.y * 64 + sl * 2];
            unsigned short g3 = *(const unsigned short*)&xq[(size_t)e3.y * 64 + sl * 2];
            unsigned short g4 = *(const unsigned short*)&xq[(size_t)e4.y * 64 + sl * 2];
            unsigned short g5 = *(const unsigned short*)&xq[(size_t)e5.y * 64 + sl * 2];
            unsigned short g6 = *(const unsigned short*)&xq[(size_t)e6.y * 64 + sl * 2];
            unsigned short g7 = *(const unsigned short*)&xq[(size_t)e7.y * 64 + sl * 2];
            float v0 = (k0 <= last) ? __int_as_float(e0.x) : 0.f;
            float v1 = (k1 <= last) ? __int_as_float(e1.x) : 0.f;
            float v2 = (k2 <= last) ? __int_as_float(e2.x) : 0.f;
            float v3 = (k3 <= last) ? __int_as_float(e3.x) : 0.f;
            float v4 = (k4 <= last) ? __int_as_float(e4.x) : 0.f;
            float v5 = (k5 <= last) ? __int_as_float(e5.x) : 0.f;
            float v6 = (k6 <= last) ? __int_as_float(e6.x) : 0.f;
            float v7 = (k7 <= last) ? __int_as_float(e7.x) : 0.f;
            a0 += v0 * Q2F((unsigned char)(g0 & 255)); a1 += v0 * Q2F((unsigned char)(g0 >> 8));
            b0 += v1 * Q2F((unsigned char)(g1 & 255)); b1 += v1 * Q2F((unsigned char)(g1 >> 8));
            c0 += v2 * Q2F((unsigned char)(g2 & 255)); c1 += v2 * Q2F((unsigned char)(g2 >> 8));
            d0 += v3 * Q2F((unsigned char)(g3 & 255)); d1 += v3 * Q2F((unsigned char)(g3 >> 8));
            a0 += v4 * Q2F((unsigned char)(g4 & 255)); a1 += v4 * Q2F((unsigned char)(g4 >> 8));
            b0 += v5 * Q2F((unsigned char)(g5 & 255)); b1 += v5 * Q2F((unsigned char)(g5 >> 8));
            c0 += v6 * Q2F((unsigned char)(g6 & 255)); c1 += v6 * Q2F((unsigned char)(g6 >> 8));
            d0 += v7 * Q2F((unsigned char)(g7 & 255)); d1 += v7 * Q2F((unsigned char)(g7 >> 8));
        }
    }
    float r0 = (a0 + b0) + (c0 + d0);
    float r1 = (a1 + b1) + (c1 + d1);
    r0 += __shfl_xor(r0, 32, 64);
    r1 += __shfl_xor(r1, 32, 64);
    if (lane < 32) {
        if (y) ((float2*)y)[(size_t)w * 32 + sl] = make_float2(r0, r1);
        if (yq) { uchar2 q; q.x = F2Q(r0); q.y = F2Q(r1); ((uchar2*)yq)[(size_t)w * 32 + sl] = q; }
    }
}

// ---------------- collapsed encoder ----------------
__global__ __launch_bounds__(256) void mc_kernel(const float* __restrict__ w0, const float* __restrict__ b0,
                                                 const float* __restrict__ w2, const float* __restrict__ b2,
                                                 float* __restrict__ Mrm, float* __restrict__ cvec) {
    int idx = blockIdx.x * 256 + threadIdx.x;
    if (idx < 4096) {
        int j = idx >> 6, d = idx & 63;
        float acc = 0.f;
        for (int k = 0; k < 256; ++k) acc += w2[j * 256 + k] * w0[k * 64 + d];
        Mrm[idx] = acc;
    } else if (idx < 4160) {
        int i = idx - 4096;
        float acc = b2[i];
        for (int k = 0; k < 256; ++k) acc += w2[i * 256 + k] * b0[k];
        cvec[i] = acc;
    }
}

// enc(f) = f @ Mrm^T + cvec ; one wave per row; fused tail+head
__global__ __launch_bounds__(256) void enc2_fused(const float* __restrict__ emb,
                                                  const int* __restrict__ tail_idx, const int* __restrict__ head_idx,
                                                  const float* __restrict__ Mrm, const float* __restrict__ cvec,
                                                  float* __restrict__ tail_e, float* __restrict__ top_e) {
    __shared__ float fsh[4][64];
    int wv = threadIdx.x >> 6, lane = threadIdx.x & 63;
    int r = blockIdx.x * 4 + wv;
    int item;
    float* outp;
    if (r < N_TAILC) { item = tail_idx[r]; outp = tail_e + (size_t)r * 64; }
    else if (r < N_TAILC + N_HEADC) { item = head_idx[r - N_TAILC]; outp = top_e + (size_t)(r - N_TAILC) * 64; }
    else { item = -1; outp = nullptr; }
    if (item >= 0) fsh[wv][lane] = emb[(size_t)item * 64 + lane];
    __syncthreads();
    if (item < 0) return;
    float acc = cvec[lane];
#pragma unroll
    for (int d4 = 0; d4 < 64; d4 += 4) {
        float4 m4 = *(const float4*)&Mrm[lane * 64 + d4];
        float4 f4 = *(const float4*)&fsh[wv][d4];
        acc += m4.x * f4.x + m4.y * f4.y + m4.z * f4.z + m4.w * f4.w;
    }
    outp[lane] = acc;
}

// ---------------- score GEMM: C[m x 4000] = A[m x 64] @ B[4000 x 64]^T ----------------
__global__ __launch_bounds__(256) void score_gemm(const float* __restrict__ A,
                                                  const float* __restrict__ B,
                                                  float* __restrict__ C, int M) {
    __shared__ float As[32][132];
    __shared__ float Bs[32][132];
    int tid = threadIdx.x;
    int tx = tid & 15, ty = tid >> 4;
    int rowbase = blockIdx.y * 128;
    int colbase = blockIdx.x * 128;
    float acc[8][8];
#pragma unroll
    for (int i = 0; i < 8; ++i)
#pragma unroll
        for (int j = 0; j < 8; ++j) acc[i][j] = 0.f;

    for (int k0 = 0; k0 < 64; k0 += 32) {
        __syncthreads();
#pragma unroll
        for (int i = 0; i < 4; ++i) {
            int f = tid + i * 256;
            int r = f >> 3;
            int kq = (f & 7) << 2;
            int grow = rowbase + r;
            float4 av = (grow < M) ? *(const float4*)&A[(size_t)grow * 64 + k0 + kq]
                                   : make_float4(0.f, 0.f, 0.f, 0.f);
            As[kq + 0][r] = av.x; As[kq + 1][r] = av.y; As[kq + 2][r] = av.z; As[kq + 3][r] = av.w;
            int gcol = colbase + r;
            float4 bv = (gcol < N_HEADC) ? *(const float4*)&B[(size_t)gcol * 64 + k0 + kq]
                                         : make_float4(0.f, 0.f, 0.f, 0.f);
            Bs[kq + 0][r] = bv.x; Bs[kq + 1][r] = bv.y; Bs[kq + 2][r] = bv.z; Bs[kq + 3][r] = bv.w;
        }
        __syncthreads();
#pragma unroll
        for (int k = 0; k < 32; ++k) {
            float a[8], b[8];
#pragma unroll
            for (int i = 0; i < 8; ++i) a[i] = As[k][ty + 16 * i];
#pragma unroll
            for (int j = 0; j < 8; ++j) b[j] = Bs[k][tx + 16 * j];
#pragma unroll
            for (int i = 0; i < 8; ++i)
#pragma unroll
                for (int j = 0; j < 8; ++j) acc[i][j] += a[i] * b[j];
        }
    }
#pragma unroll
    for (int i = 0; i < 8; ++i) {
        int r = rowbase + ty + 16 * i;
        if (r < M) {
#pragma unroll
            for (int j = 0; j < 8; ++j) {
                int c = colbase + tx + 16 * j;
                if (c < N_HEADC) C[(size_t)r * N_HEADC + c] = acc[i][j];
            }
        }
    }
}

// ---------------- per-row top-k: NAMED SCALARS ONLY ----------------
#define BUB(vk, ik) { if (cv > vk) { float tf = vk; vk = cv; cv = tf; int ti = ik; ik = ci; ci = ti; } }
#define TINS(sc, idx) { float sc_ = (sc); if (sc_ > v9) { float cv = sc_; int ci = (idx); \
    BUB(v0, i0) BUB(v1, i1) BUB(v2, i2) BUB(v3, i3) BUB(v4, i4) \
    BUB(v5, i5) BUB(v6, i6) BUB(v7, i7) BUB(v8, i8) BUB(v9, i9) } }

__global__ __launch_bounds__(256) void topk_rows(const float* __restrict__ scores, int nrows, int row0,
                                                 const int* __restrict__ head_idx,
                                                 int* __restrict__ ig_cols, float* __restrict__ ig_vals) {
    int w = (blockIdx.x * blockDim.x + threadIdx.x) >> 6;
    int lane = threadIdx.x & 63;
    if (w >= nrows) return;
    const float* srow = scores + (size_t)w * N_HEADC;
    float v0 = -1e30f, v1 = -1e30f, v2 = -1e30f, v3 = -1e30f, v4 = -1e30f;
    float v5 = -1e30f, v6 = -1e30f, v7 = -1e30f, v8 = -1e30f, v9 = -1e30f;
    int i0 = -1, i1 = -1, i2 = -1, i3 = -1, i4 = -1;
    int i5 = -1, i6 = -1, i7 = -1, i8 = -1, i9 = -1;
    for (int it = 0; it < 16; ++it) {
        int f4 = lane + it * 64;
        if (f4 < 1000) {
            float4 s4 = ((const float4*)srow)[f4];
            int cb = f4 * 4;
            TINS(s4.x, cb + 0)
            TINS(s4.y, cb + 1)
            TINS(s4.z, cb + 2)
            TINS(s4.w, cb + 3)
        }
    }
    float ssum = 0.f;
    float outv = 0.f;
    int outid = -1;
#pragma unroll
    for (int r = 0; r < TOPKC; ++r) {
        float cv = v0;
        int ci = i0;
        int wl = lane;
#pragma unroll
        for (int m = 1; m < 64; m <<= 1) {
            float ov = __shfl_xor(cv, m, 64);
            int oi = __shfl_xor(ci, m, 64);
            int ol = __shfl_xor(wl, m, 64);
            if (ov > cv || (ov == cv && ol < wl)) { cv = ov; ci = oi; wl = ol; }
        }
        if (wl == lane) {
            v0 = v1; i0 = i1; v1 = v2; i1 = i2; v2 = v3; i2 = i3;
            v3 = v4; i3 = i4; v4 = v5; i4 = i5; v5 = v6; i5 = i6;
            v6 = v7; i6 = i7; v7 = v8; i7 = i8; v8 = v9; i8 = i9;
            v9 = -1e30f; i9 = -1;
        }
        ssum += 1.f / (1.f + expf(-cv));
        if (lane == r) { outv = cv; outid = ci; }
    }
    if (lane < TOPKC) {
        float s = 1.f / (1.f + expf(-outv));
        float wgt = s / (ssum + 1.f);
        int grow = row0 + w;
        ig_vals[grow * TOPKC + lane] = wgt;
        ig_cols[grow * TOPKC + lane] = head_idx[outid];
    }
}

// ---------------- item_enh: one wave per tail row, register accumulate, 1 atomic per lane ----------------
__global__ __launch_bounds__(256) void ig_spmm_kernel(const int* __restrict__ tail_idx,
                                                      const int* __restrict__ ig_cols,
                                                      const float* __restrict__ ig_vals,
                                                      const float* __restrict__ items,
                                                      float* __restrict__ enh) {
    int r = (blockIdx.x * blockDim.x + threadIdx.x) >> 6;
    int lane = threadIdx.x & 63;
    if (r >= N_TAILC) return;
    int row = tail_idx[r];
    float acc = 0.f;
#pragma unroll
    for (int k = 0; k < TOPKC; ++k) {
        int col = ig_cols[r * TOPKC + k];
        float wgt = ig_vals[r * TOPKC + k];
        acc += wgt * items[(size_t)col * 64 + lane];
    }
    atomicAdd(&enh[(size_t)row * 64 + lane], acc);
}

// ---------------- loss: one wave per sample, per-block partial outputs ----------------
__global__ __launch_bounds__(256) void loss_kernel(const float* __restrict__ u0, const float* __restrict__ u1,
                                                   const float* __restrict__ u2, const float* __restrict__ items,
                                                   const float* __restrict__ enh, const float* __restrict__ deg,
                                                   const float* __restrict__ user_emb, const float* __restrict__ item_emb,
                                                   const int* __restrict__ bu, const int* __restrict__ bp,
                                                   const int* __restrict__ bn, float* __restrict__ part) {
    __shared__ float lsum[4], rsum[4];
    int w = (blockIdx.x * blockDim.x + threadIdx.x) >> 6;
    int wv = threadIdx.x >> 6;
    int lane = threadIdx.x & 63;
    int uu = bu[w], pp = bp[w];
    float ue = (u0[uu * 64 + lane] + u1[uu * 64 + lane] + u2[uu * 64 + lane]) * (1.f / 3.f);
    float swp = CONVF / (CONVF + expf(deg[pp] * (1.f / CONVF)));
    float pe = items[pp * 64 + lane] + swp * enh[pp * 64 + lane];
    float ps = ue * pe;
    float ns = 0.f;
    float u0e = user_emb[uu * 64 + lane];
    float p0e = item_emb[pp * 64 + lane];
    float reg = u0e * u0e + p0e * p0e;
#pragma unroll
    for (int k = 0; k < N_NEGC; ++k) {
        int nn = bn[w * N_NEGC + k];
        float swn = CONVF / (CONVF + expf(deg[nn] * (1.f / CONVF)));
        float nv = items[nn * 64 + lane] + swn * enh[nn * 64 + lane];
        ns += ue * nv;
        float n0 = item_emb[nn * 64 + lane];
        reg += n0 * n0;
    }
#pragma unroll
    for (int m = 32; m >= 1; m >>= 1) {
        ps += __shfl_xor(ps, m, 64);
        ns += __shfl_xor(ns, m, 64);
        reg += __shfl_xor(reg, m, 64);
    }
    if (lane == 0) {
        float x = ns * (1.f / N_NEGC) - ps;
        float sp = (x > 0.f) ? (x + log1pf(expf(-x))) : log1pf(expf(x));
        lsum[wv] = sp;
        rsum[wv] = reg;
    }
    __syncthreads();
    if (threadIdx.x == 0) {
        part[blockIdx.x] = lsum[0] + lsum[1] + lsum[2] + lsum[3];
        part[LOSS_BLOCKS + blockIdx.x] = rsum[0] + rsum[1] + rsum[2] + rsum[3];
    }
}

// single-block final reduce: out[0]=loss, out[1]=reg
__global__ __launch_bounds__(256) void loss_reduce(const float* __restrict__ part, float* __restrict__ out) {
    __shared__ float l[256], r[256];
    int tid = threadIdx.x;
    float a = 0.f, b = 0.f;
    for (int i = tid; i < LOSS_BLOCKS; i += 256) {
        a += part[i];
        b += part[LOSS_BLOCKS + i];
    }
    l[tid] = a; r[tid] = b;
    __syncthreads();
    for (int off = 128; off >= 1; off >>= 1) {
        if (tid < off) { l[tid] += l[tid + off]; r[tid] += r[tid + off]; }
        __syncthreads();
    }
    if (tid == 0) {
        out[0] = l[0] * (1.f / BATCHC);
        out[1] = 0.5f * r[0] * (1.f / BATCHC);
    }
}

extern "C" void kernel_launch(void* const* d_in, const int* in_sizes, int n_in,
                              void* d_out, int out_size, void* d_ws, size_t ws_size,
                              hipStream_t stream) {
    const float* user_emb = (const float*)d_in[0];
    const float* item_emb = (const float*)d_in[1];
    const float* w0 = (const float*)d_in[2];
    const float* b0 = (const float*)d_in[3];
    const float* w2 = (const float*)d_in[4];
    const float* b2 = (const float*)d_in[5];
    const float* a_vals = (const float*)d_in[6];
    const float* s_vals = (const float*)d_in[7];
    const float* item_degree = (const float*)d_in[8];
    const int* a_rows = (const int*)d_in[9];
    const int* a_cols = (const int*)d_in[10];
    const int* s_rows = (const int*)d_in[11];
    const int* s_cols = (const int*)d_in[12];
    const int* tail_idx = (const int*)d_in[13];
    const int* head_idx = (const int*)d_in[14];
    const int* batch_user = (const int*)d_in[15];
    const int* batch_pos = (const int*)d_in[16];
    const int* batch_neg = (const int*)d_in[17];
    float* out = (float*)d_out;

    // ---- workspace carve ----
    char* p = (char*)d_ws;
    auto carve = [&](size_t bytes) -> void* {
        void* r = (void*)p;
        p += (bytes + 255) & ~size_t(255);
        return r;
    };
    float* embB = (float*)carve((size_t)N_TOTALC * 64 * 4);   // final all_emb (fp32)
    float* u1 = (float*)carve((size_t)N_USERC * 64 * 4);
    float* u2 = (float*)carve((size_t)N_USERC * 64 * 4);
    float* enh = (float*)carve((size_t)N_ITEMC * 64 * 4);
    float* tail_e = (float*)carve((size_t)N_TAILC * 64 * 4);
    float* top_e = (float*)carve((size_t)N_HEADC * 64 * 4);
    int2* aSort = (int2*)carve((size_t)NB_A * SLAB * 8);      // slab layout, row-grouped
    int2* sSort = (int2*)carve((size_t)NB_S * SLAB * 8);
    int* aRs = (int*)carve((size_t)N_TOTALC * 4);
    int* aRe = (int*)carve((size_t)N_TOTALC * 4);
    int* sRs = (int*)carve((size_t)N_USERC * 4);
    int* sRe = (int*)carve((size_t)N_USERC * 4);
    int* aCur = (int*)carve((size_t)NB_A * 4);
    int* sCur = (int*)carve((size_t)NB_S * 4);
    int* ig_cols_buf = (int*)carve((size_t)N_TAILC * TOPKC * 4);
    float* ig_vals_buf = (float*)carve((size_t)N_TAILC * TOPKC * 4);
    float* Mrm = (float*)carve(64 * 64 * 4);
    float* cvec = (float*)carve(64 * 4);
    float* loss_part = (float*)carve((size_t)LOSS_BLOCKS * 2 * 4);
    float* scores = (float*)carve((size_t)CHUNK_ROWS * N_HEADC * 4);   // 40MB region, multi-phase reuse
    // aliases within the scores region (dead across phases):
    int2* aPackRaw = (int2*)scores;                           // build phase: slab raw (19.2MB)
    int2* sPackRaw = aPackRaw + (size_t)NB_A * SLAB;          // +12.8MB = 32MB < 40MB
    // after topk: fp8 tables (4 x 9.6MB = 38.4MB < 40MB)
    unsigned char* f0 = (unsigned char*)scores;               // concat input, e4m3
    unsigned char* f1 = f0 + (size_t)N_TOTALC * 64;           // L1 out
    unsigned char* f2 = f1 + (size_t)N_TOTALC * 64;           // L2 out
    unsigned char* f3 = f2 + (size_t)N_TOTALC * 64;           // L3 out
    unsigned char* uF1 = f0;                                  // S1 out (f0 dead after L1)

    // ---- slab CSR build (A + S): no histogram pass ----
    init_cursors<<<(NB_A + 255) / 256, 256, 0, stream>>>(aCur, sCur);
    partition_fused<<<PBLK_A + PBLK_S, 256, 0, stream>>>(a_vals, a_rows, a_cols,
                                                         s_vals, s_rows, s_cols,
                                                         aCur, sCur, aPackRaw, sPackRaw);
    // aCur/sCur now hold bucket END offsets within slabs
    csr_finalize<<<NB_A + NB_S, 256, 0, stream>>>(aCur, sCur, aPackRaw, sPackRaw,
                                                  aSort, sSort, aRs, aRe, sRs, sRe);

    // ---- collapsed encoder (tail + head fused) ----
    mc_kernel<<<17, 256, 0, stream>>>(w0, b0, w2, b2, Mrm, cvec);
    enc2_fused<<<(N_TAILC + N_HEADC + 3) / 4, 256, 0, stream>>>(item_emb, tail_idx, head_idx, Mrm, cvec, tail_e, top_e);

    // ---- chunked scores GEMM + top-k (slab raw dead after finalize) ----
    for (int row0 = 0; row0 < N_TAILC; row0 += CHUNK_ROWS) {
        int m = N_TAILC - row0;
        if (m > CHUNK_ROWS) m = CHUNK_ROWS;
        int rb = (m + 127) / 128;
        score_gemm<<<dim3((N_HEADC + 127) / 128, rb), 256, 0, stream>>>(tail_e + (size_t)row0 * 64, top_e, scores, m);
        topk_rows<<<(m + 3) / 4, 256, 0, stream>>>(scores, m, row0, head_idx, ig_cols_buf, ig_vals_buf);
    }

    // ---- fp8 concat input table (scores region dead from here) ----
    to_f8_concat<<<((N_TOTALC * 16) + 255) / 256, 256, 0, stream>>>(user_emb, item_emb, f0);

    // ---- 3 A-layers, fp8 clamp-predicated gathers; only L3 materializes fp32 ----
    {
        int blocks = (N_TOTALC + 3) / 4;
        spmm_f8<<<blocks, 256, 0, stream>>>(aRs, aRe, aSort, f0, nullptr, f1, N_TOTALC);  // L1
        spmm_f8<<<blocks, 256, 0, stream>>>(aRs, aRe, aSort, f1, nullptr, f2, N_TOTALC);  // L2
        spmm_f8<<<blocks, 256, 0, stream>>>(aRs, aRe, aSort, f2, embB, f3, N_TOTALC);     // L3
    }
    const float* u0 = embB;
    const float* items = embB + (size_t)N_USERC * 64;

    // ---- 2 S-layers on users ----
    {
        int blocks = (N_USERC + 3) / 4;
        spmm_f8<<<blocks, 256, 0, stream>>>(sRs, sRe, sSort, f3, u1, uF1, N_USERC);       // S1
        spmm_f8<<<blocks, 256, 0, stream>>>(sRs, sRe, sSort, uF1, u2, nullptr, N_USERC);  // S2
    }

    // ---- item enhancement ----
    hipMemsetAsync(enh, 0, (size_t)N_ITEMC * 64 * 4, stream);
    ig_spmm_kernel<<<(N_TAILC + 3) / 4, 256, 0, stream>>>(tail_idx, ig_cols_buf, ig_vals_buf, items, enh);

    // ---- loss + reg: per-block partials then single-block reduce ----
    loss_kernel<<<LOSS_BLOCKS, 256, 0, stream>>>(u0, u1, u2, items, enh, item_degree,
                                                 user_emb, item_emb, batch_user, batch_pos, batch_neg, loss_part);
    loss_reduce<<<1, 256, 0, stream>>>(loss_part, out);
}

// Round 19
// 651.767 us; speedup vs baseline: 1.6051x; 1.1300x over previous
//
#include <hip/hip_runtime.h>
#include <hip/hip_bf16.h>
#include <hip/hip_fp8.h>

#define N_USERC 100000
#define N_ITEMC 50000
#define N_TOTALC 150000
#define DC 64
#define NNZ_AC 2000000
#define NNZ_SC 1000000
#define N_TAILC 10000
#define N_HEADC 4000
#define TOPKC 10
#define BATCHC 4096
#define N_NEGC 4
#define CONVF 40.0f
#define CHUNK_ROWS 5000

#define RPB 256                                  // rows per bucket (row_local = 8 bits)
#define NB_A ((N_TOTALC + RPB - 1) / RPB)        // 586
#define NB_S ((N_USERC + RPB - 1) / RPB)         // 391
#define IPB 6144                                 // items per partition block
#define PBLK_A ((NNZ_AC + IPB - 1) / IPB)        // 326
#define PBLK_S ((NNZ_SC + IPB - 1) / IPB)        // 163
#define SLAB 4096                                // per-bucket slab capacity
#define FCAP 4096                                // finalize LDS staging capacity (32KB)

#define LOSS_BLOCKS (BATCHC / 4)                 // 1024

__device__ __forceinline__ unsigned char F2Q(float f) {
    __hip_fp8_e4m3 q(f);
    return (unsigned char)q.__x;
}
__device__ __forceinline__ float Q2F(unsigned char b) {
    __hip_fp8_e4m3 q;
    q.__x = (__hip_fp8_storage_t)b;
    return (float)q;
}
__device__ __forceinline__ unsigned short F2H(float f) {
    __hip_bfloat16 b = __float2bfloat16(f);
    return *(unsigned short*)&b;
}

// ---------------- cursor init: slab bases ----------------
__global__ __launch_bounds__(256) void init_cursors(int* __restrict__ aCur, int* __restrict__ sCur) {
    int i = blockIdx.x * 256 + threadIdx.x;
    if (i < NB_A) aCur[i] = i * SLAB;
    if (i < NB_S) sCur[i] = i * SLAB;
}

// ---------------- partition: block-local counting sort into bucket SLABS (R13 proven form) ----------------
__global__ __launch_bounds__(256) void partition_fused(
    const float* __restrict__ a_vals, const int* __restrict__ a_rows, const int* __restrict__ a_cols,
    const float* __restrict__ s_vals, const int* __restrict__ s_rows, const int* __restrict__ s_cols,
    int* __restrict__ aCur, int* __restrict__ sCur,
    int2* __restrict__ aPack, int2* __restrict__ sPack) {
    __shared__ int h[NB_A];
    __shared__ int cur[NB_A];
    int blk = blockIdx.x;
    const float* vals; const int* rows; const int* cols; int n; int nb; int* gcur; int2* pack; int base;
    if (blk < PBLK_A) { vals = a_vals; rows = a_rows; cols = a_cols; n = NNZ_AC; nb = NB_A; gcur = aCur; pack = aPack; base = blk * IPB; }
    else { vals = s_vals; rows = s_rows; cols = s_cols; n = NNZ_SC; nb = NB_S; gcur = sCur; pack = sPack; base = (blk - PBLK_A) * IPB; }
    int tid = threadIdx.x;
    for (int i = tid; i < nb; i += 256) h[i] = 0;
    __syncthreads();
    for (int k = 0; k < IPB; k += 256) {
        int idx = base + k + tid;
        if (idx < n) atomicAdd(&h[rows[idx] >> 8], 1);
    }
    __syncthreads();
    for (int i = tid; i < nb; i += 256) {
        int c = h[i];
        cur[i] = c ? atomicAdd(&gcur[i], c) : 0;
    }
    __syncthreads();
    for (int k = 0; k < IPB; k += 256) {
        int idx = base + k + tid;
        if (idx < n) {
            int r = rows[idx];
            int b = r >> 8;
            int pos = atomicAdd(&cur[b], 1);
            pack[pos] = make_int2(__float_as_int(vals[idx]), cols[idx] | ((r & 255) << 18));
        }
    }
}

// ---------------- finalize: per-bucket counting sort within slab -> rp_start / rp_end ----------------
__global__ __launch_bounds__(256) void csr_finalize(const int* __restrict__ aEnd, const int* __restrict__ sEnd,
                                                    const int2* __restrict__ aRaw, const int2* __restrict__ sRaw,
                                                    int2* __restrict__ aOut, int2* __restrict__ sOut,
                                                    int* __restrict__ aRs, int* __restrict__ aRe,
                                                    int* __restrict__ sRs, int* __restrict__ sRe) {
    __shared__ int2 ebuf[FCAP];
    __shared__ int cnt_[RPB];
    __shared__ int scn[RPB];
    __shared__ int cursor[RPB];
    int blk = blockIdx.x;
    const int* ends; const int2* raw; int2* outp; int* rs; int* re; int nrows; int b;
    if (blk < NB_A) { ends = aEnd; raw = aRaw; outp = aOut; rs = aRs; re = aRe; nrows = N_TOTALC; b = blk; }
    else { ends = sEnd; raw = sRaw; outp = sOut; rs = sRs; re = sRe; nrows = N_USERC; b = blk - NB_A; }
    int s = b * SLAB;
    int e = ends[b];
    int n = e - s;
    int tid = threadIdx.x;
    bool useLds = (n <= FCAP);
    cnt_[tid] = 0;
    __syncthreads();
    if (useLds) {
        for (int i = tid; i < n; i += 256) {
            int2 en = raw[s + i];
            ebuf[i] = en;
            atomicAdd(&cnt_[(en.y >> 18) & 255], 1);
        }
    } else {
        for (int i = tid; i < n; i += 256)
            atomicAdd(&cnt_[(raw[s + i].y >> 18) & 255], 1);
    }
    __syncthreads();
    scn[tid] = cnt_[tid];
    __syncthreads();
    for (int off = 1; off < RPB; off <<= 1) {
        int t = (tid >= off) ? scn[tid - off] : 0;
        __syncthreads();
        scn[tid] += t;
        __syncthreads();
    }
    {
        int inc = scn[tid];
        int ex = inc - cnt_[tid];
        cursor[tid] = ex;
        int row = (b << 8) + tid;
        if (row < nrows) { rs[row] = s + ex; re[row] = s + inc; }
    }
    __syncthreads();
    if (useLds) {
        for (int i = tid; i < n; i += 256) {
            int2 en = ebuf[i];
            int r = (en.y >> 18) & 255;
            int pos = atomicAdd(&cursor[r], 1);
            outp[s + pos] = make_int2(en.x, en.y & 0x3FFFF);
        }
    } else {
        for (int i = tid; i < n; i += 256) {
            int2 en = raw[s + i];
            int r = (en.y >> 18) & 255;
            int pos = atomicAdd(&cursor[r], 1);
            outp[s + pos] = make_int2(en.x, en.y & 0x3FFFF);
        }
    }
}

// ---------------- concat + fp32->fp8 convert ----------------
__global__ __launch_bounds__(256) void to_f8_concat(const float* __restrict__ xu, const float* __restrict__ xi,
                                                    unsigned char* __restrict__ out) {
    size_t i4 = (size_t)blockIdx.x * 256 + threadIdx.x;
    const size_t NU4 = (size_t)N_USERC * 16;
    const size_t NT4 = (size_t)N_TOTALC * 16;
    if (i4 >= NT4) return;
    float4 v = (i4 < NU4) ? ((const float4*)xu)[i4] : ((const float4*)xi)[i4 - NU4];
    uchar4 q;
    q.x = F2Q(v.x); q.y = F2Q(v.y); q.z = F2Q(v.z); q.w = F2Q(v.w);
    ((uchar4*)out)[i4] = q;
}

// ---------------- CSR SpMM, fp8 pair-gather, clamp-predicated 16-wide body ----------------
__global__ __launch_bounds__(256) void spmm_f8(const int* __restrict__ rps, const int* __restrict__ rpe,
                                               const int2* __restrict__ pack,
                                               const unsigned char* __restrict__ xq,
                                               float* __restrict__ y,
                                               unsigned char* __restrict__ yq, int nrows) {
    int w = (blockIdx.x * blockDim.x + threadIdx.x) >> 6;
    int lane = threadIdx.x & 63;
    if (w >= nrows) return;
    int half = lane >> 5;
    int sl = lane & 31;
    int s = rps[w], e = rpe[w];
    float a0 = 0.f, a1 = 0.f, b0 = 0.f, b1 = 0.f;
    float c0 = 0.f, c1 = 0.f, d0 = 0.f, d1 = 0.f;
    if (e > s) {
        int last = e - 1;
        for (int j = s; j < e; j += 16) {
            int k0 = j + half, k1 = k0 + 2, k2 = k0 + 4, k3 = k0 + 6;
            int k4 = k0 + 8, k5 = k0 + 10, k6 = k0 + 12, k7 = k0 + 14;
            int2 e0 = pack[min(k0, last)], e1 = pack[min(k1, last)];
            int2 e2 = pack[min(k2, last)], e3 = pack[min(k3, last)];
            int2 e4 = pack[min(k4, last)], e5 = pack[min(k5, last)];
            int2 e6 = pack[min(k6, last)], e7 = pack[min(k7, last)];
            unsigned short g0 = *(const unsigned short*)&xq[(size_t)e0.y * 64 + sl * 2];
            unsigned short g1 = *(const unsigned short*)&xq[(size_t)e1.y * 64 + sl * 2];
            unsigned short g2 = *(const unsigned short*)&xq[(size_t)e2.y * 64 + sl * 2];
            unsigned short g3 = *(const unsigned short*)&xq[(size_t)e3.y * 64 + sl * 2];
            unsigned short g4 = *(const unsigned short*)&xq[(size_t)e4.y * 64 + sl * 2];
            unsigned short g5 = *(const unsigned short*)&xq[(size_t)e5.y * 64 + sl * 2];
            unsigned short g6 = *(const unsigned short*)&xq[(size_t)e6.y * 64 + sl * 2];
            unsigned short g7 = *(const unsigned short*)&xq[(size_t)e7.y * 64 + sl * 2];
            float v0 = (k0 <= last) ? __int_as_float(e0.x) : 0.f;
            float v1 = (k1 <= last) ? __int_as_float(e1.x) : 0.f;
            float v2 = (k2 <= last) ? __int_as_float(e2.x) : 0.f;
            float v3 = (k3 <= last) ? __int_as_float(e3.x) : 0.f;
            float v4 = (k4 <= last) ? __int_as_float(e4.x) : 0.f;
            float v5 = (k5 <= last) ? __int_as_float(e5.x) : 0.f;
            float v6 = (k6 <= last) ? __int_as_float(e6.x) : 0.f;
            float v7 = (k7 <= last) ? __int_as_float(e7.x) : 0.f;
            a0 += v0 * Q2F((unsigned char)(g0 & 255)); a1 += v0 * Q2F((unsigned char)(g0 >> 8));
            b0 += v1 * Q2F((unsigned char)(g1 & 255)); b1 += v1 * Q2F((unsigned char)(g1 >> 8));
            c0 += v2 * Q2F((unsigned char)(g2 & 255)); c1 += v2 * Q2F((unsigned char)(g2 >> 8));
            d0 += v3 * Q2F((unsigned char)(g3 & 255)); d1 += v3 * Q2F((unsigned char)(g3 >> 8));
            a0 += v4 * Q2F((unsigned char)(g4 & 255)); a1 += v4 * Q2F((unsigned char)(g4 >> 8));
            b0 += v5 * Q2F((unsigned char)(g5 & 255)); b1 += v5 * Q2F((unsigned char)(g5 >> 8));
            c0 += v6 * Q2F((unsigned char)(g6 & 255)); c1 += v6 * Q2F((unsigned char)(g6 >> 8));
            d0 += v7 * Q2F((unsigned char)(g7 & 255)); d1 += v7 * Q2F((unsigned char)(g7 >> 8));
        }
    }
    float r0 = (a0 + b0) + (c0 + d0);
    float r1 = (a1 + b1) + (c1 + d1);
    r0 += __shfl_xor(r0, 32, 64);
    r1 += __shfl_xor(r1, 32, 64);
    if (lane < 32) {
        if (y) ((float2*)y)[(size_t)w * 32 + sl] = make_float2(r0, r1);
        if (yq) { uchar2 q; q.x = F2Q(r0); q.y = F2Q(r1); ((uchar2*)yq)[(size_t)w * 32 + sl] = q; }
    }
}

// ---------------- collapsed encoder ----------------
__global__ __launch_bounds__(256) void mc_kernel(const float* __restrict__ w0, const float* __restrict__ b0,
                                                 const float* __restrict__ w2, const float* __restrict__ b2,
                                                 float* __restrict__ Mrm, float* __restrict__ cvec) {
    int idx = blockIdx.x * 256 + threadIdx.x;
    if (idx < 4096) {
        int j = idx >> 6, d = idx & 63;
        float acc = 0.f;
        for (int k = 0; k < 256; ++k) acc += w2[j * 256 + k] * w0[k * 64 + d];
        Mrm[idx] = acc;
    } else if (idx < 4160) {
        int i = idx - 4096;
        float acc = b2[i];
        for (int k = 0; k < 256; ++k) acc += w2[i * 256 + k] * b0[k];
        cvec[i] = acc;
    }
}

// enc(f) = f @ Mrm^T + cvec ; one wave per row; fused tail+head
__global__ __launch_bounds__(256) void enc2_fused(const float* __restrict__ emb,
                                                  const int* __restrict__ tail_idx, const int* __restrict__ head_idx,
                                                  const float* __restrict__ Mrm, const float* __restrict__ cvec,
                                                  float* __restrict__ tail_e, float* __restrict__ top_e) {
    __shared__ float fsh[4][64];
    int wv = threadIdx.x >> 6, lane = threadIdx.x & 63;
    int r = blockIdx.x * 4 + wv;
    int item;
    float* outp;
    if (r < N_TAILC) { item = tail_idx[r]; outp = tail_e + (size_t)r * 64; }
    else if (r < N_TAILC + N_HEADC) { item = head_idx[r - N_TAILC]; outp = top_e + (size_t)(r - N_TAILC) * 64; }
    else { item = -1; outp = nullptr; }
    if (item >= 0) fsh[wv][lane] = emb[(size_t)item * 64 + lane];
    __syncthreads();
    if (item < 0) return;
    float acc = cvec[lane];
#pragma unroll
    for (int d4 = 0; d4 < 64; d4 += 4) {
        float4 m4 = *(const float4*)&Mrm[lane * 64 + d4];
        float4 f4 = *(const float4*)&fsh[wv][d4];
        acc += m4.x * f4.x + m4.y * f4.y + m4.z * f4.z + m4.w * f4.w;
    }
    outp[lane] = acc;
}

// ---------------- score GEMM: C[m x 4000] bf16 = A[m x 64] @ B[4000 x 64]^T ----------------
__global__ __launch_bounds__(256) void score_gemm(const float* __restrict__ A,
                                                  const float* __restrict__ B,
                                                  unsigned short* __restrict__ C, int M) {
    __shared__ float As[32][132];
    __shared__ float Bs[32][132];
    int tid = threadIdx.x;
    int tx = tid & 15, ty = tid >> 4;
    int rowbase = blockIdx.y * 128;
    int colbase = blockIdx.x * 128;
    float acc[8][8];
#pragma unroll
    for (int i = 0; i < 8; ++i)
#pragma unroll
        for (int j = 0; j < 8; ++j) acc[i][j] = 0.f;

    for (int k0 = 0; k0 < 64; k0 += 32) {
        __syncthreads();
#pragma unroll
        for (int i = 0; i < 4; ++i) {
            int f = tid + i * 256;
            int r = f >> 3;
            int kq = (f & 7) << 2;
            int grow = rowbase + r;
            float4 av = (grow < M) ? *(const float4*)&A[(size_t)grow * 64 + k0 + kq]
                                   : make_float4(0.f, 0.f, 0.f, 0.f);
            As[kq + 0][r] = av.x; As[kq + 1][r] = av.y; As[kq + 2][r] = av.z; As[kq + 3][r] = av.w;
            int gcol = colbase + r;
            float4 bv = (gcol < N_HEADC) ? *(const float4*)&B[(size_t)gcol * 64 + k0 + kq]
                                         : make_float4(0.f, 0.f, 0.f, 0.f);
            Bs[kq + 0][r] = bv.x; Bs[kq + 1][r] = bv.y; Bs[kq + 2][r] = bv.z; Bs[kq + 3][r] = bv.w;
        }
        __syncthreads();
#pragma unroll
        for (int k = 0; k < 32; ++k) {
            float a[8], b[8];
#pragma unroll
            for (int i = 0; i < 8; ++i) a[i] = As[k][ty + 16 * i];
#pragma unroll
            for (int j = 0; j < 8; ++j) b[j] = Bs[k][tx + 16 * j];
#pragma unroll
            for (int i = 0; i < 8; ++i)
#pragma unroll
                for (int j = 0; j < 8; ++j) acc[i][j] += a[i] * b[j];
        }
    }
#pragma unroll
    for (int i = 0; i < 8; ++i) {
        int r = rowbase + ty + 16 * i;
        if (r < M) {
#pragma unroll
            for (int j = 0; j < 8; ++j) {
                int c = colbase + tx + 16 * j;
                if (c < N_HEADC) C[(size_t)r * N_HEADC + c] = F2H(acc[i][j]);
            }
        }
    }
}

// ---------------- per-row top-k on bf16 scores: NAMED SCALARS ONLY ----------------
#define BUB(vk, ik) { if (cv > vk) { float tf = vk; vk = cv; cv = tf; int ti = ik; ik = ci; ci = ti; } }
#define TINS(sc, idx) { float sc_ = (sc); if (sc_ > v9) { float cv = sc_; int ci = (idx); \
    BUB(v0, i0) BUB(v1, i1) BUB(v2, i2) BUB(v3, i3) BUB(v4, i4) \
    BUB(v5, i5) BUB(v6, i6) BUB(v7, i7) BUB(v8, i8) BUB(v9, i9) } }
#define BLO(u) __uint_as_float((u) << 16)
#define BHI(u) __uint_as_float((u) & 0xFFFF0000u)

__global__ __launch_bounds__(256) void topk_rows(const unsigned short* __restrict__ scores, int nrows, int row0,
                                                 const int* __restrict__ head_idx,
                                                 int* __restrict__ ig_cols, float* __restrict__ ig_vals) {
    int w = (blockIdx.x * blockDim.x + threadIdx.x) >> 6;
    int lane = threadIdx.x & 63;
    if (w >= nrows) return;
    const unsigned short* srow = scores + (size_t)w * N_HEADC;
    float v0 = -1e30f, v1 = -1e30f, v2 = -1e30f, v3 = -1e30f, v4 = -1e30f;
    float v5 = -1e30f, v6 = -1e30f, v7 = -1e30f, v8 = -1e30f, v9 = -1e30f;
    int i0 = -1, i1 = -1, i2 = -1, i3 = -1, i4 = -1;
    int i5 = -1, i6 = -1, i7 = -1, i8 = -1, i9 = -1;
    // 4000 bf16 = 500 x (8 bf16 per uint4); lanes stride 64
    for (int it = 0; it < 8; ++it) {
        int f8 = lane + it * 64;
        if (f8 < 500) {
            uint4 s8 = ((const uint4*)srow)[f8];
            int cb = f8 * 8;
            TINS(BLO(s8.x), cb + 0)
            TINS(BHI(s8.x), cb + 1)
            TINS(BLO(s8.y), cb + 2)
            TINS(BHI(s8.y), cb + 3)
            TINS(BLO(s8.z), cb + 4)
            TINS(BHI(s8.z), cb + 5)
            TINS(BLO(s8.w), cb + 6)
            TINS(BHI(s8.w), cb + 7)
        }
    }
    float ssum = 0.f;
    float outv = 0.f;
    int outid = -1;
#pragma unroll
    for (int r = 0; r < TOPKC; ++r) {
        float cv = v0;
        int ci = i0;
        int wl = lane;
#pragma unroll
        for (int m = 1; m < 64; m <<= 1) {
            float ov = __shfl_xor(cv, m, 64);
            int oi = __shfl_xor(ci, m, 64);
            int ol = __shfl_xor(wl, m, 64);
            if (ov > cv || (ov == cv && ol < wl)) { cv = ov; ci = oi; wl = ol; }
        }
        if (wl == lane) {
            v0 = v1; i0 = i1; v1 = v2; i1 = i2; v2 = v3; i2 = i3;
            v3 = v4; i3 = i4; v4 = v5; i4 = i5; v5 = v6; i5 = i6;
            v6 = v7; i6 = i7; v7 = v8; i7 = i8; v8 = v9; i8 = i9;
            v9 = -1e30f; i9 = -1;
        }
        ssum += 1.f / (1.f + expf(-cv));
        if (lane == r) { outv = cv; outid = ci; }
    }
    if (lane < TOPKC) {
        float s = 1.f / (1.f + expf(-outv));
        float wgt = s / (ssum + 1.f);
        int grow = row0 + w;
        ig_vals[grow * TOPKC + lane] = wgt;
        ig_cols[grow * TOPKC + lane] = head_idx[outid];
    }
}

// ---------------- item_enh: one wave per tail row, register accumulate, 1 atomic per lane ----------------
__global__ __launch_bounds__(256) void ig_spmm_kernel(const int* __restrict__ tail_idx,
                                                      const int* __restrict__ ig_cols,
                                                      const float* __restrict__ ig_vals,
                                                      const float* __restrict__ items,
                                                      float* __restrict__ enh) {
    int r = (blockIdx.x * blockDim.x + threadIdx.x) >> 6;
    int lane = threadIdx.x & 63;
    if (r >= N_TAILC) return;
    int row = tail_idx[r];
    float acc = 0.f;
#pragma unroll
    for (int k = 0; k < TOPKC; ++k) {
        int col = ig_cols[r * TOPKC + k];
        float wgt = ig_vals[r * TOPKC + k];
        acc += wgt * items[(size_t)col * 64 + lane];
    }
    atomicAdd(&enh[(size_t)row * 64 + lane], acc);
}

// ---------------- loss: one wave per sample, per-block partial outputs ----------------
__global__ __launch_bounds__(256) void loss_kernel(const float* __restrict__ u0, const float* __restrict__ u1,
                                                   const float* __restrict__ u2, const float* __restrict__ items,
                                                   const float* __restrict__ enh, const float* __restrict__ deg,
                                                   const float* __restrict__ user_emb, const float* __restrict__ item_emb,
                                                   const int* __restrict__ bu, const int* __restrict__ bp,
                                                   const int* __restrict__ bn, float* __restrict__ part) {
    __shared__ float lsum[4], rsum[4];
    int w = (blockIdx.x * blockDim.x + threadIdx.x) >> 6;
    int wv = threadIdx.x >> 6;
    int lane = threadIdx.x & 63;
    int uu = bu[w], pp = bp[w];
    float ue = (u0[uu * 64 + lane] + u1[uu * 64 + lane] + u2[uu * 64 + lane]) * (1.f / 3.f);
    float swp = CONVF / (CONVF + expf(deg[pp] * (1.f / CONVF)));
    float pe = items[pp * 64 + lane] + swp * enh[pp * 64 + lane];
    float ps = ue * pe;
    float ns = 0.f;
    float u0e = user_emb[uu * 64 + lane];
    float p0e = item_emb[pp * 64 + lane];
    float reg = u0e * u0e + p0e * p0e;
#pragma unroll
    for (int k = 0; k < N_NEGC; ++k) {
        int nn = bn[w * N_NEGC + k];
        float swn = CONVF / (CONVF + expf(deg[nn] * (1.f / CONVF)));
        float nv = items[nn * 64 + lane] + swn * enh[nn * 64 + lane];
        ns += ue * nv;
        float n0 = item_emb[nn * 64 + lane];
        reg += n0 * n0;
    }
#pragma unroll
    for (int m = 32; m >= 1; m >>= 1) {
        ps += __shfl_xor(ps, m, 64);
        ns += __shfl_xor(ns, m, 64);
        reg += __shfl_xor(reg, m, 64);
    }
    if (lane == 0) {
        float x = ns * (1.f / N_NEGC) - ps;
        float sp = (x > 0.f) ? (x + log1pf(expf(-x))) : log1pf(expf(x));
        lsum[wv] = sp;
        rsum[wv] = reg;
    }
    __syncthreads();
    if (threadIdx.x == 0) {
        part[blockIdx.x] = lsum[0] + lsum[1] + lsum[2] + lsum[3];
        part[LOSS_BLOCKS + blockIdx.x] = rsum[0] + rsum[1] + rsum[2] + rsum[3];
    }
}

// single-block final reduce: out[0]=loss, out[1]=reg
__global__ __launch_bounds__(256) void loss_reduce(const float* __restrict__ part, float* __restrict__ out) {
    __shared__ float l[256], r[256];
    int tid = threadIdx.x;
    float a = 0.f, b = 0.f;
    for (int i = tid; i < LOSS_BLOCKS; i += 256) {
        a += part[i];
        b += part[LOSS_BLOCKS + i];
    }
    l[tid] = a; r[tid] = b;
    __syncthreads();
    for (int off = 128; off >= 1; off >>= 1) {
        if (tid < off) { l[tid] += l[tid + off]; r[tid] += r[tid + off]; }
        __syncthreads();
    }
    if (tid == 0) {
        out[0] = l[0] * (1.f / BATCHC);
        out[1] = 0.5f * r[0] * (1.f / BATCHC);
    }
}

extern "C" void kernel_launch(void* const* d_in, const int* in_sizes, int n_in,
                              void* d_out, int out_size, void* d_ws, size_t ws_size,
                              hipStream_t stream) {
    const float* user_emb = (const float*)d_in[0];
    const float* item_emb = (const float*)d_in[1];
    const float* w0 = (const float*)d_in[2];
    const float* b0 = (const float*)d_in[3];
    const float* w2 = (const float*)d_in[4];
    const float* b2 = (const float*)d_in[5];
    const float* a_vals = (const float*)d_in[6];
    const float* s_vals = (const float*)d_in[7];
    const float* item_degree = (const float*)d_in[8];
    const int* a_rows = (const int*)d_in[9];
    const int* a_cols = (const int*)d_in[10];
    const int* s_rows = (const int*)d_in[11];
    const int* s_cols = (const int*)d_in[12];
    const int* tail_idx = (const int*)d_in[13];
    const int* head_idx = (const int*)d_in[14];
    const int* batch_user = (const int*)d_in[15];
    const int* batch_pos = (const int*)d_in[16];
    const int* batch_neg = (const int*)d_in[17];
    float* out = (float*)d_out;

    // ---- workspace carve ----
    char* p = (char*)d_ws;
    auto carve = [&](size_t bytes) -> void* {
        void* r = (void*)p;
        p += (bytes + 255) & ~size_t(255);
        return r;
    };
    float* embB = (float*)carve((size_t)N_TOTALC * 64 * 4);   // final all_emb (fp32)
    float* u1 = (float*)carve((size_t)N_USERC * 64 * 4);
    float* u2 = (float*)carve((size_t)N_USERC * 64 * 4);
    float* enh = (float*)carve((size_t)N_ITEMC * 64 * 4);
    float* tail_e = (float*)carve((size_t)N_TAILC * 64 * 4);
    float* top_e = (float*)carve((size_t)N_HEADC * 64 * 4);
    int2* aSort = (int2*)carve((size_t)NB_A * SLAB * 8);      // slab layout, row-grouped
    int2* sSort = (int2*)carve((size_t)NB_S * SLAB * 8);
    int* aRs = (int*)carve((size_t)N_TOTALC * 4);
    int* aRe = (int*)carve((size_t)N_TOTALC * 4);
    int* sRs = (int*)carve((size_t)N_USERC * 4);
    int* sRe = (int*)carve((size_t)N_USERC * 4);
    int* aCur = (int*)carve((size_t)NB_A * 4);
    int* sCur = (int*)carve((size_t)NB_S * 4);
    int* ig_cols_buf = (int*)carve((size_t)N_TAILC * TOPKC * 4);
    float* ig_vals_buf = (float*)carve((size_t)N_TAILC * TOPKC * 4);
    float* Mrm = (float*)carve(64 * 64 * 4);
    float* cvec = (float*)carve(64 * 4);
    float* loss_part = (float*)carve((size_t)LOSS_BLOCKS * 2 * 4);
    char* scratch = (char*)carve((size_t)40 * 1024 * 1024);   // 40MB multi-phase region
    // aliases within the scratch region (dead across phases):
    int2* aPackRaw = (int2*)scratch;                          // build phase: slab raw (19.2MB)
    int2* sPackRaw = aPackRaw + (size_t)NB_A * SLAB;          // +12.8MB = 32MB < 40MB
    unsigned short* scores = (unsigned short*)scratch;        // score phase: bf16 5000x4000 = 40MB
    // after topk: fp8 tables (4 x 9.6MB = 38.4MB < 40MB)
    unsigned char* f0 = (unsigned char*)scratch;              // concat input, e4m3
    unsigned char* f1 = f0 + (size_t)N_TOTALC * 64;           // L1 out
    unsigned char* f2 = f1 + (size_t)N_TOTALC * 64;           // L2 out
    unsigned char* f3 = f2 + (size_t)N_TOTALC * 64;           // L3 out
    unsigned char* uF1 = f0;                                  // S1 out (f0 dead after L1)

    // ---- slab CSR build (A + S): no histogram pass ----
    init_cursors<<<(NB_A + 255) / 256, 256, 0, stream>>>(aCur, sCur);
    partition_fused<<<PBLK_A + PBLK_S, 256, 0, stream>>>(a_vals, a_rows, a_cols,
                                                         s_vals, s_rows, s_cols,
                                                         aCur, sCur, aPackRaw, sPackRaw);
    // aCur/sCur now hold bucket END offsets within slabs
    csr_finalize<<<NB_A + NB_S, 256, 0, stream>>>(aCur, sCur, aPackRaw, sPackRaw,
                                                  aSort, sSort, aRs, aRe, sRs, sRe);

    // ---- collapsed encoder (tail + head fused) ----
    mc_kernel<<<17, 256, 0, stream>>>(w0, b0, w2, b2, Mrm, cvec);
    enc2_fused<<<(N_TAILC + N_HEADC + 3) / 4, 256, 0, stream>>>(item_emb, tail_idx, head_idx, Mrm, cvec, tail_e, top_e);

    // ---- chunked bf16 scores GEMM + top-k (slab raw dead after finalize) ----
    for (int row0 = 0; row0 < N_TAILC; row0 += CHUNK_ROWS) {
        int m = N_TAILC - row0;
        if (m > CHUNK_ROWS) m = CHUNK_ROWS;
        int rb = (m + 127) / 128;
        score_gemm<<<dim3((N_HEADC + 127) / 128, rb), 256, 0, stream>>>(tail_e + (size_t)row0 * 64, top_e, scores, m);
        topk_rows<<<(m + 3) / 4, 256, 0, stream>>>(scores, m, row0, head_idx, ig_cols_buf, ig_vals_buf);
    }

    // ---- fp8 concat input table (scores dead from here) ----
    to_f8_concat<<<((N_TOTALC * 16) + 255) / 256, 256, 0, stream>>>(user_emb, item_emb, f0);

    // ---- 3 A-layers, fp8 clamp-predicated gathers; only L3 materializes fp32 ----
    {
        int blocks = (N_TOTALC + 3) / 4;
        spmm_f8<<<blocks, 256, 0, stream>>>(aRs, aRe, aSort, f0, nullptr, f1, N_TOTALC);  // L1
        spmm_f8<<<blocks, 256, 0, stream>>>(aRs, aRe, aSort, f1, nullptr, f2, N_TOTALC);  // L2
        spmm_f8<<<blocks, 256, 0, stream>>>(aRs, aRe, aSort, f2, embB, f3, N_TOTALC);     // L3
    }
    const float* u0 = embB;
    const float* items = embB + (size_t)N_USERC * 64;

    // ---- 2 S-layers on users ----
    {
        int blocks = (N_USERC + 3) / 4;
        spmm_f8<<<blocks, 256, 0, stream>>>(sRs, sRe, sSort, f3, u1, uF1, N_USERC);       // S1
        spmm_f8<<<blocks, 256, 0, stream>>>(sRs, sRe, sSort, uF1, u2, nullptr, N_USERC);  // S2
    }

    // ---- item enhancement ----
    hipMemsetAsync(enh, 0, (size_t)N_ITEMC * 64 * 4, stream);
    ig_spmm_kernel<<<(N_TAILC + 3) / 4, 256, 0, stream>>>(tail_idx, ig_cols_buf, ig_vals_buf, items, enh);

    // ---- loss + reg: per-block partials then single-block reduce ----
    loss_kernel<<<LOSS_BLOCKS, 256, 0, stream>>>(u0, u1, u2, items, enh, item_degree,
                                                 user_emb, item_emb, batch_user, batch_pos, batch_neg, loss_part);
    loss_reduce<<<1, 256, 0, stream>>>(loss_part, out);
}

// Round 20
// 547.661 us; speedup vs baseline: 1.9102x; 1.1901x over previous
//
#include <hip/hip_runtime.h>
#include <hip/hip_bf16.h>
#include <hip/hip_fp8.h>

#define N_USERC 100000
#define N_ITEMC 50000
#define N_TOTALC 150000
#define DC 64
#define NNZ_AC 2000000
#define NNZ_SC 1000000
#define N_TAILC 10000
#define N_HEADC 4000
#define TOPKC 10
#define BATCHC 4096
#define N_NEGC 4
#define CONVF 40.0f
#define CHUNK_ROWS 5000

#define RPB 256                                  // rows per bucket (row_local = 8 bits)
#define NB_A ((N_TOTALC + RPB - 1) / RPB)        // 586
#define NB_S ((N_USERC + RPB - 1) / RPB)         // 391
#define IPB 6144                                 // items per partition block
#define PBLK_A ((NNZ_AC + IPB - 1) / IPB)        // 326
#define PBLK_S ((NNZ_SC + IPB - 1) / IPB)        // 163
#define SLAB 4096                                // per-bucket slab capacity
#define FCAP 4096                                // finalize LDS staging capacity (32KB)
#define NCG 125                                  // col groups of 32 (4000/32)
#define RT_CHUNK ((CHUNK_ROWS + 15) / 16)        // 313 row tiles per chunk

#define LOSS_BLOCKS (BATCHC / 4)                 // 1024

typedef __attribute__((ext_vector_type(8))) short short8v;   // 8 bf16 (4 VGPRs)
typedef __attribute__((ext_vector_type(4))) float f32x4;     // MFMA acc

__device__ __forceinline__ unsigned char F2Q(float f) {
    __hip_fp8_e4m3 q(f);
    return (unsigned char)q.__x;
}
__device__ __forceinline__ float Q2F(unsigned char b) {
    __hip_fp8_e4m3 q;
    q.__x = (__hip_fp8_storage_t)b;
    return (float)q;
}
__device__ __forceinline__ unsigned short F2H(float f) {
    __hip_bfloat16 b = __float2bfloat16(f);
    return *(unsigned short*)&b;
}

// ---------------- cursor init: slab bases ----------------
__global__ __launch_bounds__(256) void init_cursors(int* __restrict__ aCur, int* __restrict__ sCur) {
    int i = blockIdx.x * 256 + threadIdx.x;
    if (i < NB_A) aCur[i] = i * SLAB;
    if (i < NB_S) sCur[i] = i * SLAB;
}

// ---------------- partition: block-local counting sort into bucket SLABS (R13 proven form) ----------------
__global__ __launch_bounds__(256) void partition_fused(
    const float* __restrict__ a_vals, const int* __restrict__ a_rows, const int* __restrict__ a_cols,
    const float* __restrict__ s_vals, const int* __restrict__ s_rows, const int* __restrict__ s_cols,
    int* __restrict__ aCur, int* __restrict__ sCur,
    int2* __restrict__ aPack, int2* __restrict__ sPack) {
    __shared__ int h[NB_A];
    __shared__ int cur[NB_A];
    int blk = blockIdx.x;
    const float* vals; const int* rows; const int* cols; int n; int nb; int* gcur; int2* pack; int base;
    if (blk < PBLK_A) { vals = a_vals; rows = a_rows; cols = a_cols; n = NNZ_AC; nb = NB_A; gcur = aCur; pack = aPack; base = blk * IPB; }
    else { vals = s_vals; rows = s_rows; cols = s_cols; n = NNZ_SC; nb = NB_S; gcur = sCur; pack = sPack; base = (blk - PBLK_A) * IPB; }
    int tid = threadIdx.x;
    for (int i = tid; i < nb; i += 256) h[i] = 0;
    __syncthreads();
    for (int k = 0; k < IPB; k += 256) {
        int idx = base + k + tid;
        if (idx < n) atomicAdd(&h[rows[idx] >> 8], 1);
    }
    __syncthreads();
    for (int i = tid; i < nb; i += 256) {
        int c = h[i];
        cur[i] = c ? atomicAdd(&gcur[i], c) : 0;
    }
    __syncthreads();
    for (int k = 0; k < IPB; k += 256) {
        int idx = base + k + tid;
        if (idx < n) {
            int r = rows[idx];
            int b = r >> 8;
            int pos = atomicAdd(&cur[b], 1);
            pack[pos] = make_int2(__float_as_int(vals[idx]), cols[idx] | ((r & 255) << 18));
        }
    }
}

// ---------------- finalize: per-bucket counting sort within slab -> rp_start / rp_end ----------------
__global__ __launch_bounds__(256) void csr_finalize(const int* __restrict__ aEnd, const int* __restrict__ sEnd,
                                                    const int2* __restrict__ aRaw, const int2* __restrict__ sRaw,
                                                    int2* __restrict__ aOut, int2* __restrict__ sOut,
                                                    int* __restrict__ aRs, int* __restrict__ aRe,
                                                    int* __restrict__ sRs, int* __restrict__ sRe) {
    __shared__ int2 ebuf[FCAP];
    __shared__ int cnt_[RPB];
    __shared__ int scn[RPB];
    __shared__ int cursor[RPB];
    int blk = blockIdx.x;
    const int* ends; const int2* raw; int2* outp; int* rs; int* re; int nrows; int b;
    if (blk < NB_A) { ends = aEnd; raw = aRaw; outp = aOut; rs = aRs; re = aRe; nrows = N_TOTALC; b = blk; }
    else { ends = sEnd; raw = sRaw; outp = sOut; rs = sRs; re = sRe; nrows = N_USERC; b = blk - NB_A; }
    int s = b * SLAB;
    int e = ends[b];
    int n = e - s;
    int tid = threadIdx.x;
    bool useLds = (n <= FCAP);
    cnt_[tid] = 0;
    __syncthreads();
    if (useLds) {
        for (int i = tid; i < n; i += 256) {
            int2 en = raw[s + i];
            ebuf[i] = en;
            atomicAdd(&cnt_[(en.y >> 18) & 255], 1);
        }
    } else {
        for (int i = tid; i < n; i += 256)
            atomicAdd(&cnt_[(raw[s + i].y >> 18) & 255], 1);
    }
    __syncthreads();
    scn[tid] = cnt_[tid];
    __syncthreads();
    for (int off = 1; off < RPB; off <<= 1) {
        int t = (tid >= off) ? scn[tid - off] : 0;
        __syncthreads();
        scn[tid] += t;
        __syncthreads();
    }
    {
        int inc = scn[tid];
        int ex = inc - cnt_[tid];
        cursor[tid] = ex;
        int row = (b << 8) + tid;
        if (row < nrows) { rs[row] = s + ex; re[row] = s + inc; }
    }
    __syncthreads();
    if (useLds) {
        for (int i = tid; i < n; i += 256) {
            int2 en = ebuf[i];
            int r = (en.y >> 18) & 255;
            int pos = atomicAdd(&cursor[r], 1);
            outp[s + pos] = make_int2(en.x, en.y & 0x3FFFF);
        }
    } else {
        for (int i = tid; i < n; i += 256) {
            int2 en = raw[s + i];
            int r = (en.y >> 18) & 255;
            int pos = atomicAdd(&cursor[r], 1);
            outp[s + pos] = make_int2(en.x, en.y & 0x3FFFF);
        }
    }
}

// ---------------- concat + fp32->fp8 convert ----------------
__global__ __launch_bounds__(256) void to_f8_concat(const float* __restrict__ xu, const float* __restrict__ xi,
                                                    unsigned char* __restrict__ out) {
    size_t i4 = (size_t)blockIdx.x * 256 + threadIdx.x;
    const size_t NU4 = (size_t)N_USERC * 16;
    const size_t NT4 = (size_t)N_TOTALC * 16;
    if (i4 >= NT4) return;
    float4 v = (i4 < NU4) ? ((const float4*)xu)[i4] : ((const float4*)xi)[i4 - NU4];
    uchar4 q;
    q.x = F2Q(v.x); q.y = F2Q(v.y); q.z = F2Q(v.z); q.w = F2Q(v.w);
    ((uchar4*)out)[i4] = q;
}

// ---------------- CSR SpMM, fp8 pair-gather, clamp-predicated 16-wide body ----------------
__global__ __launch_bounds__(256) void spmm_f8(const int* __restrict__ rps, const int* __restrict__ rpe,
                                               const int2* __restrict__ pack,
                                               const unsigned char* __restrict__ xq,
                                               float* __restrict__ y,
                                               unsigned char* __restrict__ yq, int nrows) {
    int w = (blockIdx.x * blockDim.x + threadIdx.x) >> 6;
    int lane = threadIdx.x & 63;
    if (w >= nrows) return;
    int half = lane >> 5;
    int sl = lane & 31;
    int s = rps[w], e = rpe[w];
    float a0 = 0.f, a1 = 0.f, b0 = 0.f, b1 = 0.f;
    float c0 = 0.f, c1 = 0.f, d0 = 0.f, d1 = 0.f;
    if (e > s) {
        int last = e - 1;
        for (int j = s; j < e; j += 16) {
            int k0 = j + half, k1 = k0 + 2, k2 = k0 + 4, k3 = k0 + 6;
            int k4 = k0 + 8, k5 = k0 + 10, k6 = k0 + 12, k7 = k0 + 14;
            int2 e0 = pack[min(k0, last)], e1 = pack[min(k1, last)];
            int2 e2 = pack[min(k2, last)], e3 = pack[min(k3, last)];
            int2 e4 = pack[min(k4, last)], e5 = pack[min(k5, last)];
            int2 e6 = pack[min(k6, last)], e7 = pack[min(k7, last)];
            unsigned short g0 = *(const unsigned short*)&xq[(size_t)e0.y * 64 + sl * 2];
            unsigned short g1 = *(const unsigned short*)&xq[(size_t)e1.y * 64 + sl * 2];
            unsigned short g2 = *(const unsigned short*)&xq[(size_t)e2.y * 64 + sl * 2];
            unsigned short g3 = *(const unsigned short*)&xq[(size_t)e3.y * 64 + sl * 2];
            unsigned short g4 = *(const unsigned short*)&xq[(size_t)e4.y * 64 + sl * 2];
            unsigned short g5 = *(const unsigned short*)&xq[(size_t)e5.y * 64 + sl * 2];
            unsigned short g6 = *(const unsigned short*)&xq[(size_t)e6.y * 64 + sl * 2];
            unsigned short g7 = *(const unsigned short*)&xq[(size_t)e7.y * 64 + sl * 2];
            float v0 = (k0 <= last) ? __int_as_float(e0.x) : 0.f;
            float v1 = (k1 <= last) ? __int_as_float(e1.x) : 0.f;
            float v2 = (k2 <= last) ? __int_as_float(e2.x) : 0.f;
            float v3 = (k3 <= last) ? __int_as_float(e3.x) : 0.f;
            float v4 = (k4 <= last) ? __int_as_float(e4.x) : 0.f;
            float v5 = (k5 <= last) ? __int_as_float(e5.x) : 0.f;
            float v6 = (k6 <= last) ? __int_as_float(e6.x) : 0.f;
            float v7 = (k7 <= last) ? __int_as_float(e7.x) : 0.f;
            a0 += v0 * Q2F((unsigned char)(g0 & 255)); a1 += v0 * Q2F((unsigned char)(g0 >> 8));
            b0 += v1 * Q2F((unsigned char)(g1 & 255)); b1 += v1 * Q2F((unsigned char)(g1 >> 8));
            c0 += v2 * Q2F((unsigned char)(g2 & 255)); c1 += v2 * Q2F((unsigned char)(g2 >> 8));
            d0 += v3 * Q2F((unsigned char)(g3 & 255)); d1 += v3 * Q2F((unsigned char)(g3 >> 8));
            a0 += v4 * Q2F((unsigned char)(g4 & 255)); a1 += v4 * Q2F((unsigned char)(g4 >> 8));
            b0 += v5 * Q2F((unsigned char)(g5 & 255)); b1 += v5 * Q2F((unsigned char)(g5 >> 8));
            c0 += v6 * Q2F((unsigned char)(g6 & 255)); c1 += v6 * Q2F((unsigned char)(g6 >> 8));
            d0 += v7 * Q2F((unsigned char)(g7 & 255)); d1 += v7 * Q2F((unsigned char)(g7 >> 8));
        }
    }
    float r0 = (a0 + b0) + (c0 + d0);
    float r1 = (a1 + b1) + (c1 + d1);
    r0 += __shfl_xor(r0, 32, 64);
    r1 += __shfl_xor(r1, 32, 64);
    if (lane < 32) {
        if (y) ((float2*)y)[(size_t)w * 32 + sl] = make_float2(r0, r1);
        if (yq) { uchar2 q; q.x = F2Q(r0); q.y = F2Q(r1); ((uchar2*)yq)[(size_t)w * 32 + sl] = q; }
    }
}

// ---------------- collapsed encoder ----------------
__global__ __launch_bounds__(256) void mc_kernel(const float* __restrict__ w0, const float* __restrict__ b0,
                                                 const float* __restrict__ w2, const float* __restrict__ b2,
                                                 float* __restrict__ Mrm, float* __restrict__ cvec) {
    int idx = blockIdx.x * 256 + threadIdx.x;
    if (idx < 4096) {
        int j = idx >> 6, d = idx & 63;
        float acc = 0.f;
        for (int k = 0; k < 256; ++k) acc += w2[j * 256 + k] * w0[k * 64 + d];
        Mrm[idx] = acc;
    } else if (idx < 4160) {
        int i = idx - 4096;
        float acc = b2[i];
        for (int k = 0; k < 256; ++k) acc += w2[i * 256 + k] * b0[k];
        cvec[i] = acc;
    }
}

// enc(f) = f @ Mrm^T + cvec ; one wave per row; fused tail+head; bf16 outputs
__global__ __launch_bounds__(256) void enc2_fused(const float* __restrict__ emb,
                                                  const int* __restrict__ tail_idx, const int* __restrict__ head_idx,
                                                  const float* __restrict__ Mrm, const float* __restrict__ cvec,
                                                  unsigned short* __restrict__ tail_e, unsigned short* __restrict__ top_e) {
    __shared__ float fsh[4][64];
    int wv = threadIdx.x >> 6, lane = threadIdx.x & 63;
    int r = blockIdx.x * 4 + wv;
    int item;
    unsigned short* outp;
    if (r < N_TAILC) { item = tail_idx[r]; outp = tail_e + (size_t)r * 64; }
    else if (r < N_TAILC + N_HEADC) { item = head_idx[r - N_TAILC]; outp = top_e + (size_t)(r - N_TAILC) * 64; }
    else { item = -1; outp = nullptr; }
    if (item >= 0) fsh[wv][lane] = emb[(size_t)item * 64 + lane];
    __syncthreads();
    if (item < 0) return;
    float acc = cvec[lane];
#pragma unroll
    for (int d4 = 0; d4 < 64; d4 += 4) {
        float4 m4 = *(const float4*)&Mrm[lane * 64 + d4];
        float4 f4 = *(const float4*)&fsh[wv][d4];
        acc += m4.x * f4.x + m4.y * f4.y + m4.z * f4.z + m4.w * f4.w;
    }
    outp[lane] = F2H(acc);
}

// ---------------- MFMA score GEMM: C[m x 4000] bf16 = A[m x 64] @ B[4000 x 64]^T ----------------
// one wave = 16 rows x 32 cols; fragments loaded directly from row-major bf16 tables
// A frag: lane l, j -> A[l&15][(l>>4)*8+j]; B frag: lane l, j -> B_col (l&15), k (l>>4)*8+j = top[col][k]
// D frag: lane l, reg q -> row (l>>4)*4+q, col l&15   (guide m89/m91 verified)
__global__ __launch_bounds__(256) void score_gemm_mfma(const unsigned short* __restrict__ AH,
                                                       const unsigned short* __restrict__ BH,
                                                       unsigned short* __restrict__ C, int M) {
    int gw = (blockIdx.x * 256 + threadIdx.x) >> 6;
    int lane = threadIdx.x & 63;
    int RT = (M + 15) >> 4;
    if (gw >= RT * NCG) return;
    int rt = gw / NCG, cg = gw % NCG;
    int rowbase = rt << 4, colbase = cg << 5;
    int r = lane & 15, kg = lane >> 4;
    int arow = rowbase + r; if (arow >= M) arow = M - 1;
    const short8v a0 = *(const short8v*)(AH + (size_t)arow * 64 + kg * 8);
    const short8v a1 = *(const short8v*)(AH + (size_t)arow * 64 + 32 + kg * 8);
    const unsigned short* b0p = BH + (size_t)(colbase + r) * 64 + kg * 8;
    const unsigned short* b1p = BH + (size_t)(colbase + 16 + r) * 64 + kg * 8;
    const short8v b00 = *(const short8v*)(b0p);
    const short8v b01 = *(const short8v*)(b0p + 32);
    const short8v b10 = *(const short8v*)(b1p);
    const short8v b11 = *(const short8v*)(b1p + 32);
    f32x4 acc0 = {0.f, 0.f, 0.f, 0.f};
    f32x4 acc1 = {0.f, 0.f, 0.f, 0.f};
    acc0 = __builtin_amdgcn_mfma_f32_16x16x32_bf16(a0, b00, acc0, 0, 0, 0);
    acc0 = __builtin_amdgcn_mfma_f32_16x16x32_bf16(a1, b01, acc0, 0, 0, 0);
    acc1 = __builtin_amdgcn_mfma_f32_16x16x32_bf16(a0, b10, acc1, 0, 0, 0);
    acc1 = __builtin_amdgcn_mfma_f32_16x16x32_bf16(a1, b11, acc1, 0, 0, 0);
#pragma unroll
    for (int q = 0; q < 4; ++q) {
        int row = rowbase + (kg << 2) + q;
        if (row < M) {
            C[(size_t)row * N_HEADC + colbase + r] = F2H(acc0[q]);
            C[(size_t)row * N_HEADC + colbase + 16 + r] = F2H(acc1[q]);
        }
    }
}

// ---------------- per-row top-k on bf16 scores: NAMED SCALARS ONLY ----------------
#define BUB(vk, ik) { if (cv > vk) { float tf = vk; vk = cv; cv = tf; int ti = ik; ik = ci; ci = ti; } }
#define TINS(sc, idx) { float sc_ = (sc); if (sc_ > v9) { float cv = sc_; int ci = (idx); \
    BUB(v0, i0) BUB(v1, i1) BUB(v2, i2) BUB(v3, i3) BUB(v4, i4) \
    BUB(v5, i5) BUB(v6, i6) BUB(v7, i7) BUB(v8, i8) BUB(v9, i9) } }
#define BLO(u) __uint_as_float((u) << 16)
#define BHI(u) __uint_as_float((u) & 0xFFFF0000u)

__global__ __launch_bounds__(256) void topk_rows(const unsigned short* __restrict__ scores, int nrows, int row0,
                                                 const int* __restrict__ head_idx,
                                                 int* __restrict__ ig_cols, float* __restrict__ ig_vals) {
    int w = (blockIdx.x * blockDim.x + threadIdx.x) >> 6;
    int lane = threadIdx.x & 63;
    if (w >= nrows) return;
    const unsigned short* srow = scores + (size_t)w * N_HEADC;
    float v0 = -1e30f, v1 = -1e30f, v2 = -1e30f, v3 = -1e30f, v4 = -1e30f;
    float v5 = -1e30f, v6 = -1e30f, v7 = -1e30f, v8 = -1e30f, v9 = -1e30f;
    int i0 = -1, i1 = -1, i2 = -1, i3 = -1, i4 = -1;
    int i5 = -1, i6 = -1, i7 = -1, i8 = -1, i9 = -1;
    for (int it = 0; it < 8; ++it) {
        int f8 = lane + it * 64;
        if (f8 < 500) {
            uint4 s8 = ((const uint4*)srow)[f8];
            int cb = f8 * 8;
            TINS(BLO(s8.x), cb + 0)
            TINS(BHI(s8.x), cb + 1)
            TINS(BLO(s8.y), cb + 2)
            TINS(BHI(s8.y), cb + 3)
            TINS(BLO(s8.z), cb + 4)
            TINS(BHI(s8.z), cb + 5)
            TINS(BLO(s8.w), cb + 6)
            TINS(BHI(s8.w), cb + 7)
        }
    }
    float ssum = 0.f;
    float outv = 0.f;
    int outid = -1;
#pragma unroll
    for (int r = 0; r < TOPKC; ++r) {
        float cv = v0;
        int ci = i0;
        int wl = lane;
#pragma unroll
        for (int m = 1; m < 64; m <<= 1) {
            float ov = __shfl_xor(cv, m, 64);
            int oi = __shfl_xor(ci, m, 64);
            int ol = __shfl_xor(wl, m, 64);
            if (ov > cv || (ov == cv && ol < wl)) { cv = ov; ci = oi; wl = ol; }
        }
        if (wl == lane) {
            v0 = v1; i0 = i1; v1 = v2; i1 = i2; v2 = v3; i2 = i3;
            v3 = v4; i3 = i4; v4 = v5; i4 = i5; v5 = v6; i5 = i6;
            v6 = v7; i6 = i7; v7 = v8; i7 = i8; v8 = v9; i8 = i9;
            v9 = -1e30f; i9 = -1;
        }
        ssum += 1.f / (1.f + expf(-cv));
        if (lane == r) { outv = cv; outid = ci; }
    }
    if (lane < TOPKC) {
        float s = 1.f / (1.f + expf(-outv));
        float wgt = s / (ssum + 1.f);
        int grow = row0 + w;
        ig_vals[grow * TOPKC + lane] = wgt;
        ig_cols[grow * TOPKC + lane] = head_idx[outid];
    }
}

// ---------------- item_enh: one wave per tail row, register accumulate, 1 atomic per lane ----------------
__global__ __launch_bounds__(256) void ig_spmm_kernel(const int* __restrict__ tail_idx,
                                                      const int* __restrict__ ig_cols,
                                                      const float* __restrict__ ig_vals,
                                                      const float* __restrict__ items,
                                                      float* __restrict__ enh) {
    int r = (blockIdx.x * blockDim.x + threadIdx.x) >> 6;
    int lane = threadIdx.x & 63;
    if (r >= N_TAILC) return;
    int row = tail_idx[r];
    float acc = 0.f;
#pragma unroll
    for (int k = 0; k < TOPKC; ++k) {
        int col = ig_cols[r * TOPKC + k];
        float wgt = ig_vals[r * TOPKC + k];
        acc += wgt * items[(size_t)col * 64 + lane];
    }
    atomicAdd(&enh[(size_t)row * 64 + lane], acc);
}

// ---------------- loss: one wave per sample, per-block partial outputs ----------------
__global__ __launch_bounds__(256) void loss_kernel(const float* __restrict__ u0, const float* __restrict__ u1,
                                                   const float* __restrict__ u2, const float* __restrict__ items,
                                                   const float* __restrict__ enh, const float* __restrict__ deg,
                                                   const float* __restrict__ user_emb, const float* __restrict__ item_emb,
                                                   const int* __restrict__ bu, const int* __restrict__ bp,
                                                   const int* __restrict__ bn, float* __restrict__ part) {
    __shared__ float lsum[4], rsum[4];
    int w = (blockIdx.x * blockDim.x + threadIdx.x) >> 6;
    int wv = threadIdx.x >> 6;
    int lane = threadIdx.x & 63;
    int uu = bu[w], pp = bp[w];
    float ue = (u0[uu * 64 + lane] + u1[uu * 64 + lane] + u2[uu * 64 + lane]) * (1.f / 3.f);
    float swp = CONVF / (CONVF + expf(deg[pp] * (1.f / CONVF)));
    float pe = items[pp * 64 + lane] + swp * enh[pp * 64 + lane];
    float ps = ue * pe;
    float ns = 0.f;
    float u0e = user_emb[uu * 64 + lane];
    float p0e = item_emb[pp * 64 + lane];
    float reg = u0e * u0e + p0e * p0e;
#pragma unroll
    for (int k = 0; k < N_NEGC; ++k) {
        int nn = bn[w * N_NEGC + k];
        float swn = CONVF / (CONVF + expf(deg[nn] * (1.f / CONVF)));
        float nv = items[nn * 64 + lane] + swn * enh[nn * 64 + lane];
        ns += ue * nv;
        float n0 = item_emb[nn * 64 + lane];
        reg += n0 * n0;
    }
#pragma unroll
    for (int m = 32; m >= 1; m >>= 1) {
        ps += __shfl_xor(ps, m, 64);
        ns += __shfl_xor(ns, m, 64);
        reg += __shfl_xor(reg, m, 64);
    }
    if (lane == 0) {
        float x = ns * (1.f / N_NEGC) - ps;
        float sp = (x > 0.f) ? (x + log1pf(expf(-x))) : log1pf(expf(x));
        lsum[wv] = sp;
        rsum[wv] = reg;
    }
    __syncthreads();
    if (threadIdx.x == 0) {
        part[blockIdx.x] = lsum[0] + lsum[1] + lsum[2] + lsum[3];
        part[LOSS_BLOCKS + blockIdx.x] = rsum[0] + rsum[1] + rsum[2] + rsum[3];
    }
}

// single-block final reduce: out[0]=loss, out[1]=reg
__global__ __launch_bounds__(256) void loss_reduce(const float* __restrict__ part, float* __restrict__ out) {
    __shared__ float l[256], r[256];
    int tid = threadIdx.x;
    float a = 0.f, b = 0.f;
    for (int i = tid; i < LOSS_BLOCKS; i += 256) {
        a += part[i];
        b += part[LOSS_BLOCKS + i];
    }
    l[tid] = a; r[tid] = b;
    __syncthreads();
    for (int off = 128; off >= 1; off >>= 1) {
        if (tid < off) { l[tid] += l[tid + off]; r[tid] += r[tid + off]; }
        __syncthreads();
    }
    if (tid == 0) {
        out[0] = l[0] * (1.f / BATCHC);
        out[1] = 0.5f * r[0] * (1.f / BATCHC);
    }
}

extern "C" void kernel_launch(void* const* d_in, const int* in_sizes, int n_in,
                              void* d_out, int out_size, void* d_ws, size_t ws_size,
                              hipStream_t stream) {
    const float* user_emb = (const float*)d_in[0];
    const float* item_emb = (const float*)d_in[1];
    const float* w0 = (const float*)d_in[2];
    const float* b0 = (const float*)d_in[3];
    const float* w2 = (const float*)d_in[4];
    const float* b2 = (const float*)d_in[5];
    const float* a_vals = (const float*)d_in[6];
    const float* s_vals = (const float*)d_in[7];
    const float* item_degree = (const float*)d_in[8];
    const int* a_rows = (const int*)d_in[9];
    const int* a_cols = (const int*)d_in[10];
    const int* s_rows = (const int*)d_in[11];
    const int* s_cols = (const int*)d_in[12];
    const int* tail_idx = (const int*)d_in[13];
    const int* head_idx = (const int*)d_in[14];
    const int* batch_user = (const int*)d_in[15];
    const int* batch_pos = (const int*)d_in[16];
    const int* batch_neg = (const int*)d_in[17];
    float* out = (float*)d_out;

    // ---- workspace carve ----
    char* p = (char*)d_ws;
    auto carve = [&](size_t bytes) -> void* {
        void* r = (void*)p;
        p += (bytes + 255) & ~size_t(255);
        return r;
    };
    float* embB = (float*)carve((size_t)N_TOTALC * 64 * 4);   // final all_emb (fp32)
    float* u1 = (float*)carve((size_t)N_USERC * 64 * 4);
    float* u2 = (float*)carve((size_t)N_USERC * 64 * 4);
    float* enh = (float*)carve((size_t)N_ITEMC * 64 * 4);
    unsigned short* tail_e = (unsigned short*)carve((size_t)N_TAILC * 64 * 2);   // bf16
    unsigned short* top_e = (unsigned short*)carve((size_t)N_HEADC * 64 * 2);    // bf16
    int2* aSort = (int2*)carve((size_t)NB_A * SLAB * 8);      // slab layout, row-grouped
    int2* sSort = (int2*)carve((size_t)NB_S * SLAB * 8);
    int* aRs = (int*)carve((size_t)N_TOTALC * 4);
    int* aRe = (int*)carve((size_t)N_TOTALC * 4);
    int* sRs = (int*)carve((size_t)N_USERC * 4);
    int* sRe = (int*)carve((size_t)N_USERC * 4);
    int* aCur = (int*)carve((size_t)NB_A * 4);
    int* sCur = (int*)carve((size_t)NB_S * 4);
    int* ig_cols_buf = (int*)carve((size_t)N_TAILC * TOPKC * 4);
    float* ig_vals_buf = (float*)carve((size_t)N_TAILC * TOPKC * 4);
    float* Mrm = (float*)carve(64 * 64 * 4);
    float* cvec = (float*)carve(64 * 4);
    float* loss_part = (float*)carve((size_t)LOSS_BLOCKS * 2 * 4);
    char* scratch = (char*)carve((size_t)40 * 1024 * 1024);   // 40MB multi-phase region
    // aliases within the scratch region (dead across phases):
    int2* aPackRaw = (int2*)scratch;                          // build phase: slab raw (19.2MB)
    int2* sPackRaw = aPackRaw + (size_t)NB_A * SLAB;          // +12.8MB = 32MB < 40MB
    unsigned short* scores = (unsigned short*)scratch;        // score phase: bf16 5000x4000 = 40MB
    // after topk: fp8 tables (4 x 9.6MB = 38.4MB < 40MB)
    unsigned char* f0 = (unsigned char*)scratch;              // concat input, e4m3
    unsigned char* f1 = f0 + (size_t)N_TOTALC * 64;           // L1 out
    unsigned char* f2 = f1 + (size_t)N_TOTALC * 64;           // L2 out
    unsigned char* f3 = f2 + (size_t)N_TOTALC * 64;           // L3 out
    unsigned char* uF1 = f0;                                  // S1 out (f0 dead after L1)

    // ---- slab CSR build (A + S): no histogram pass ----
    init_cursors<<<(NB_A + 255) / 256, 256, 0, stream>>>(aCur, sCur);
    partition_fused<<<PBLK_A + PBLK_S, 256, 0, stream>>>(a_vals, a_rows, a_cols,
                                                         s_vals, s_rows, s_cols,
                                                         aCur, sCur, aPackRaw, sPackRaw);
    // aCur/sCur now hold bucket END offsets within slabs
    csr_finalize<<<NB_A + NB_S, 256, 0, stream>>>(aCur, sCur, aPackRaw, sPackRaw,
                                                  aSort, sSort, aRs, aRe, sRs, sRe);

    // ---- collapsed encoder (tail + head fused), bf16 outputs ----
    mc_kernel<<<17, 256, 0, stream>>>(w0, b0, w2, b2, Mrm, cvec);
    enc2_fused<<<(N_TAILC + N_HEADC + 3) / 4, 256, 0, stream>>>(item_emb, tail_idx, head_idx, Mrm, cvec, tail_e, top_e);

    // ---- chunked MFMA scores GEMM + top-k (slab raw dead after finalize) ----
    for (int row0 = 0; row0 < N_TAILC; row0 += CHUNK_ROWS) {
        int m = N_TAILC - row0;
        if (m > CHUNK_ROWS) m = CHUNK_ROWS;
        int waves = ((m + 15) / 16) * NCG;
        score_gemm_mfma<<<(waves + 3) / 4, 256, 0, stream>>>(tail_e + (size_t)row0 * 64, top_e, scores, m);
        topk_rows<<<(m + 3) / 4, 256, 0, stream>>>(scores, m, row0, head_idx, ig_cols_buf, ig_vals_buf);
    }

    // ---- fp8 concat input table (scores dead from here) ----
    to_f8_concat<<<((N_TOTALC * 16) + 255) / 256, 256, 0, stream>>>(user_emb, item_emb, f0);

    // ---- 3 A-layers, fp8 clamp-predicated gathers; only L3 materializes fp32 ----
    {
        int blocks = (N_TOTALC + 3) / 4;
        spmm_f8<<<blocks, 256, 0, stream>>>(aRs, aRe, aSort, f0, nullptr, f1, N_TOTALC);  // L1
        spmm_f8<<<blocks, 256, 0, stream>>>(aRs, aRe, aSort, f1, nullptr, f2, N_TOTALC);  // L2
        spmm_f8<<<blocks, 256, 0, stream>>>(aRs, aRe, aSort, f2, embB, f3, N_TOTALC);     // L3
    }
    const float* u0 = embB;
    const float* items = embB + (size_t)N_USERC * 64;

    // ---- 2 S-layers on users ----
    {
        int blocks = (N_USERC + 3) / 4;
        spmm_f8<<<blocks, 256, 0, stream>>>(sRs, sRe, sSort, f3, u1, uF1, N_USERC);       // S1
        spmm_f8<<<blocks, 256, 0, stream>>>(sRs, sRe, sSort, uF1, u2, nullptr, N_USERC);  // S2
    }

    // ---- item enhancement ----
    hipMemsetAsync(enh, 0, (size_t)N_ITEMC * 64 * 4, stream);
    ig_spmm_kernel<<<(N_TAILC + 3) / 4, 256, 0, stream>>>(tail_idx, ig_cols_buf, ig_vals_buf, items, enh);

    // ---- loss + reg: per-block partials then single-block reduce ----
    loss_kernel<<<LOSS_BLOCKS, 256, 0, stream>>>(u0, u1, u2, items, enh, item_degree,
                                                 user_emb, item_emb, batch_user, batch_pos, batch_neg, loss_part);
    loss_reduce<<<1, 256, 0, stream>>>(loss_part, out);
}